// Round 2
// baseline (728.360 us; speedup 1.0000x reference)
//
#include <hip/hip_runtime.h>
#include <hip/hip_bf16.h>

// Problem constants (from reference): N=50000, E=800000, D=128, H=256, A=16
#define N_NODES 50000
#define N_EDGES 800000
#define DIM_D   128
#define DIM_H   256
#define DIM_A   16

typedef unsigned short u16;
typedef __attribute__((ext_vector_type(4))) float f4;
typedef __attribute__((ext_vector_type(8))) short s8;
typedef __attribute__((ext_vector_type(4))) short s4;

__device__ __forceinline__ u16 f2bf(float f) {
    union { float f; unsigned u; } v; v.f = f;
    unsigned r = v.u + 0x7FFFu + ((v.u >> 16) & 1u);   // RNE
    return (u16)(r >> 16);
}
__device__ __forceinline__ float bf2f(u16 s) {
    union { unsigned u; float f; } v; v.u = ((unsigned)s) << 16; return v.f;
}
__device__ __forceinline__ s8 zero_s8() {
    s8 v;
#pragma unroll
    for (int i = 0; i < 8; i++) v[i] = 0;
    return v;
}

// ---------------- CSR build ----------------
__global__ __launch_bounds__(256) void k_zero(int* __restrict__ cnt) {
    int i = blockIdx.x * 256 + threadIdx.x;
    if (i < N_NODES) cnt[i] = 0;
}
__global__ __launch_bounds__(256) void k_count(const int* __restrict__ coli, int* __restrict__ cnt) {
    int e = blockIdx.x * 256 + threadIdx.x;
    if (e < N_EDGES) atomicAdd(&cnt[coli[e]], 1);
}
__global__ __launch_bounds__(256) void k_dinv(const int* __restrict__ cnt, float* __restrict__ dinv) {
    int i = blockIdx.x * 256 + threadIdx.x;
    if (i < N_NODES) dinv[i] = rsqrtf((float)(cnt[i] + 1));   // +1 self-loop
}

#define SCAN_C 49   // 1024 * 49 = 50176 >= N_NODES
__global__ __launch_bounds__(1024) void k_scan(const int* __restrict__ cnt, int* __restrict__ start) {
    __shared__ int ps[1024];
    int t = threadIdx.x;
    int base = t * SCAN_C;
    int sum = 0;
    for (int i = 0; i < SCAN_C; i++) {
        int idx = base + i;
        sum += (idx < N_NODES) ? cnt[idx] : 0;
    }
    ps[t] = sum;
    __syncthreads();
    for (int ofs = 1; ofs < 1024; ofs <<= 1) {
        int v = (t >= ofs) ? ps[t - ofs] : 0;
        __syncthreads();
        ps[t] += v;
        __syncthreads();
    }
    int run = (t > 0) ? ps[t - 1] : 0;
    for (int i = 0; i < SCAN_C; i++) {
        int idx = base + i;
        if (idx < N_NODES) {
            start[idx] = run;
            run += cnt[idx];
        }
    }
    if (t == 1023) start[N_NODES] = ps[1023];
}
__global__ __launch_bounds__(256) void k_copy(const int* __restrict__ start, int* __restrict__ cursor) {
    int i = blockIdx.x * 256 + threadIdx.x;
    if (i < N_NODES) cursor[i] = start[i];
}
// pack[slot] = {src_node, dinv[src]*dinv[dst]} bucketed by destination
// eidx[slot] = {orig_edge, dst_node} (for CSR-ordered edge predictor)
__global__ __launch_bounds__(256) void k_fill(const int* __restrict__ rowi, const int* __restrict__ coli,
                                              const float* __restrict__ dinv,
                                              int* __restrict__ cursor, int2* __restrict__ pack,
                                              int2* __restrict__ eidx) {
    int e = blockIdx.x * 256 + threadIdx.x;
    if (e >= N_EDGES) return;
    int r = rowi[e], c = coli[e];
    int slot = atomicAdd(&cursor[c], 1);
    float w = dinv[r] * dinv[c];
    pack[slot] = make_int2(r, __float_as_int(w));
    eidx[slot] = make_int2(e, c);
}

// ---------------- fp32 -> bf16 cast (x table) ----------------
__global__ __launch_bounds__(256) void k_cast(const float* __restrict__ X, u16* __restrict__ Y, int n4) {
    int i = blockIdx.x * 256 + threadIdx.x;
    if (i >= n4) return;
    float4 v = *(const float4*)&X[(size_t)i * 4];
    ushort4 o;
    o.x = f2bf(v.x); o.y = f2bf(v.y); o.z = f2bf(v.z); o.w = f2bf(v.w);
    *(ushort4*)&Y[(size_t)i * 4] = o;
}

// ---------------- CSR gather: z[n] = X[n]*dinv[n]^2 + sum_{e->n} X[src]*w ----------------
// one wave per node; two 32-lane halves process alternate CSR entries, lane covers 4 cols (bf16 X)
__global__ __launch_bounds__(256) void k_gather(const u16* __restrict__ X,
                                                const int2* __restrict__ pack,
                                                const int* __restrict__ start,
                                                const float* __restrict__ dinv,
                                                float* __restrict__ z) {
    int node = blockIdx.x * 4 + (threadIdx.x >> 6);
    if (node >= N_NODES) return;
    int lane = threadIdx.x & 63;
    int half = lane >> 5, j = lane & 31;
    int c4 = j * 4;
    float di = dinv[node];
    f4 acc = {0.f, 0.f, 0.f, 0.f};
    if (half == 0) {
        float sl = di * di;
        ushort4 u = *(const ushort4*)&X[(size_t)node * DIM_D + c4];
        acc[0] = bf2f(u.x) * sl; acc[1] = bf2f(u.y) * sl;
        acc[2] = bf2f(u.z) * sl; acc[3] = bf2f(u.w) * sl;
    }
    int s = start[node], e = start[node + 1];
#pragma unroll 8
    for (int i = s + half; i < e; i += 2) {
        int2 p = pack[i];
        float w = __int_as_float(p.y);
        ushort4 u = *(const ushort4*)&X[(size_t)p.x * DIM_D + c4];
        acc[0] += bf2f(u.x) * w; acc[1] += bf2f(u.y) * w;
        acc[2] += bf2f(u.z) * w; acc[3] += bf2f(u.w) * w;
    }
    // combine halves: lane j (<32) += lane j+32
    float t0 = acc[0] + __shfl(acc[0], j + 32);
    float t1 = acc[1] + __shfl(acc[1], j + 32);
    float t2 = acc[2] + __shfl(acc[2], j + 32);
    float t3 = acc[3] + __shfl(acc[3], j + 32);
    if (half == 0)
        *(float4*)&z[(size_t)node * DIM_D + c4] = make_float4(t0, t1, t2, t3);
}

// ---------------- weight transpose+cast: W[K][Nn] fp32 -> Wt[Nn][K] bf16 ----------------
__global__ __launch_bounds__(256) void k_twt(const float* __restrict__ W, u16* __restrict__ Wt,
                                             int K, int Nn) {
    int idx = blockIdx.x * 256 + threadIdx.x;
    if (idx >= K * Nn) return;
    int k = idx / Nn, n = idx - k * Nn;
    Wt[n * K + k] = f2bf(W[idx]);
}

// combined edge-predictor bias: bpq[0..255]=be1, bpq[256..511]=0
__global__ __launch_bounds__(256) void k_bpq(const float* __restrict__ be1, float* __restrict__ bpq) {
    int i = blockIdx.x * 256 + threadIdx.x;
    if (i < 512) bpq[i] = (i < 256) ? be1[i] : 0.f;
}

// ---------------- MFMA GEMM: C[M][Nn] = post(A[M][K] @ W + postB), W given as Wt[Nn][K] bf16 ----
// A_BF16: A is bf16[M][K] else fp32. PRE_BR: A' = relu(A + preB[k]) before cast.
#define BM 128
#define BN 64
#define BK 32
#define BKP 56   // padded K stride in LDS (bf16 elems)

template <bool A_BF16, bool PRE_BR, bool POST_RELU, bool OUT_BF16>
__global__ __launch_bounds__(256) void k_gemm(const void* __restrict__ Ap,
                                              const u16* __restrict__ Wt,
                                              const float* __restrict__ preB,
                                              const float* __restrict__ postB,
                                              void* __restrict__ Cp,
                                              int M, int K, int Nn) {
    __shared__ __align__(16) u16 As[BM * BKP];
    __shared__ __align__(16) u16 Bs[BN * BKP];
    const int tid = threadIdx.x;
    const int wid = tid >> 6, lane = tid & 63;
    const int q = lane >> 4, l = lane & 15;
    const int bm = blockIdx.x * BM, bn = blockIdx.y * BN;

    f4 acc[8];
#pragma unroll
    for (int i = 0; i < 8; i++) { f4 zz = {0.f, 0.f, 0.f, 0.f}; acc[i] = zz; }

    for (int k0 = 0; k0 < K; k0 += BK) {
        __syncthreads();
        // stage W tile: Bs[n][k], n in [bn,bn+64), k in [k0,k0+32)
        {
            int n = tid >> 2, kc = (tid & 3) * 8;
            *(int4*)&Bs[n * BKP + kc] = *(const int4*)&Wt[(size_t)(bn + n) * K + k0 + kc];
        }
        // stage A tile: As[m][k]
        if (A_BF16) {
            const u16* A = (const u16*)Ap;
#pragma unroll
            for (int p = 0; p < 2; p++) {
                int m = (tid >> 2) + p * 64, kc = (tid & 3) * 8;
                int gm = bm + m; if (gm >= M) gm = M - 1;
                *(int4*)&As[m * BKP + kc] = *(const int4*)&A[(size_t)gm * K + k0 + kc];
            }
        } else {
            const float* A = (const float*)Ap;
#pragma unroll
            for (int p = 0; p < 4; p++) {
                int m = (tid >> 3) + p * 32, k4 = (tid & 7) * 4;
                int gm = bm + m; if (gm >= M) gm = M - 1;
                float4 v = *(const float4*)&A[(size_t)gm * K + k0 + k4];
                if (PRE_BR) {
                    const float4 pb = *(const float4*)&preB[k0 + k4];
                    v.x = fmaxf(v.x + pb.x, 0.f);
                    v.y = fmaxf(v.y + pb.y, 0.f);
                    v.z = fmaxf(v.z + pb.z, 0.f);
                    v.w = fmaxf(v.w + pb.w, 0.f);
                }
                ushort4 o;
                o.x = f2bf(v.x); o.y = f2bf(v.y); o.z = f2bf(v.z); o.w = f2bf(v.w);
                *(ushort4*)&As[m * BKP + k4] = o;
            }
        }
        __syncthreads();

        s8 af[2], bf[4];
#pragma unroll
        for (int mt = 0; mt < 2; mt++)
            af[mt] = *(const s8*)&As[(wid * 32 + mt * 16 + l) * BKP + q * 8];
#pragma unroll
        for (int nt = 0; nt < 4; nt++)
            bf[nt] = *(const s8*)&Bs[(nt * 16 + l) * BKP + q * 8];
#pragma unroll
        for (int mt = 0; mt < 2; mt++)
#pragma unroll
            for (int nt = 0; nt < 4; nt++)
                acc[mt * 4 + nt] = __builtin_amdgcn_mfma_f32_16x16x32_bf16(
                    af[mt], bf[nt], acc[mt * 4 + nt], 0, 0, 0);
    }

    // epilogue: C row = q*4+r, col = l (per 16x16 tile)
#pragma unroll
    for (int mt = 0; mt < 2; mt++) {
#pragma unroll
        for (int nt = 0; nt < 4; nt++) {
            int colg = bn + nt * 16 + l;
            float pb = postB ? postB[colg] : 0.0f;
#pragma unroll
            for (int r = 0; r < 4; r++) {
                int rowg = bm + wid * 32 + mt * 16 + q * 4 + r;
                if (rowg < M) {
                    float v = acc[mt * 4 + nt][r] + pb;
                    if (POST_RELU) v = fmaxf(v, 0.f);
                    if (OUT_BF16)
                        ((u16*)Cp)[(size_t)rowg * Nn + colg] = f2bf(v);
                    else
                        ((float*)Cp)[(size_t)rowg * Nn + colg] = v;
                }
            }
        }
    }
}

// ---------------- edge predictor: 16 edges (CSR slots) per wave -----------------------------
// CSR-ordered (Q gathers hit same lines across lanes). v3: force deep MLP —
//  * Wct fragments hoisted out of the tile loop (tile-invariant, were re-read 16x/tile)
//  * all 32 P/Q gathers + attr issued, then sched_barrier(0) pins them ABOVE the MFMA chain
//    (round-1 showed the scheduler sinks them back to use sites: VGPR stayed 56)
//  * next tile's pack/eidx prefetched before compute (breaks the idx->gather dependent chain)
#if __has_builtin(__builtin_amdgcn_mfma_f32_16x16x16bf16_1k)
__global__ __launch_bounds__(256) void k_edge(const u16* __restrict__ PQ,     // [N][512]: P|Q
                                              const float* __restrict__ attr,
                                              const int2* __restrict__ pack,
                                              const int2* __restrict__ eidx,
                                              const u16* __restrict__ Wct,    // [256][16] bf16
                                              const u16* __restrict__ We2t,   // [16][256] bf16
                                              const float* __restrict__ be2,
                                              float* __restrict__ outp) {
    const int tid = threadIdx.x, wid = tid >> 6, lane = tid & 63;
    const int q = lane >> 4, l = lane & 15;
    const float4 be2v = *(const float4*)&be2[q * 4];
    const int NT = N_EDGES / 16;
    const int step = gridDim.x * 4;

    // tile-invariant fragments in registers: We2^T A-frags + Wc^T A-frags
    s4 we2f[16], wcf[16];
#pragma unroll
    for (int mt = 0; mt < 16; mt++) {
        we2f[mt] = *(const s4*)&We2t[(size_t)l * DIM_H + mt * 16 + q * 4];
        wcf[mt]  = *(const s4*)&Wct[(mt * 16 + l) * 16 + q * 4];
    }

    int tile = blockIdx.x * 4 + wid;
    if (tile >= NT) return;
    int2 pk = pack[tile * 16 + l];        // {src, weight(unused)}
    int2 ec = eidx[tile * 16 + l];        // {orig edge, dst}

    for (; tile < NT; tile += step) {
        const int re = pk.x, e = ec.x, ce = ec.y;
        const u16* prow = PQ + (size_t)re * 512 + q * 4;          // P half (random, LLC)
        const u16* qrow = PQ + (size_t)ce * 512 + 256 + q * 4;    // Q half (CSR runs, L1)

        // issue the whole gather batch: attr + 32 P/Q fragments
        float4 av = *(const float4*)&attr[(size_t)e * DIM_A + q * 4];
        ushort4 pu[16], qu[16];
#pragma unroll
        for (int mt = 0; mt < 16; mt++) {
            pu[mt] = *(const ushort4*)(prow + mt * 16);
            qu[mt] = *(const ushort4*)(qrow + mt * 16);
        }
        // prefetch next tile's indices (independent of current compute)
        int ntile = tile + step;
        int ns = (ntile < NT) ? ntile * 16 + l : l;
        int2 pk_n = pack[ns];
        int2 ec_n = eidx[ns];
        // fence: nothing above may sink below — all 35 loads stay in flight over the math
        __builtin_amdgcn_sched_barrier(0);

        s4 af;   // attr B-frag: B[k=q*4+j][n=edge=l]
        af[0] = (short)f2bf(av.x); af[1] = (short)f2bf(av.y);
        af[2] = (short)f2bf(av.z); af[3] = (short)f2bf(av.w);

        f4 acc2 = {0.f, 0.f, 0.f, 0.f};
#pragma unroll
        for (int mt = 0; mt < 16; mt++) {
            f4 cz = {0.f, 0.f, 0.f, 0.f};
            f4 acc = __builtin_amdgcn_mfma_f32_16x16x16bf16_1k(wcf[mt], af, cz, 0, 0, 0);
            float t0 = bf2f(pu[mt].x) + bf2f(qu[mt].x) + acc[0];
            float t1 = bf2f(pu[mt].y) + bf2f(qu[mt].y) + acc[1];
            float t2 = bf2f(pu[mt].z) + bf2f(qu[mt].z) + acc[2];
            float t3 = bf2f(pu[mt].w) + bf2f(qu[mt].w) + acc[3];
            s4 uf;   // B-frag of u^T: lane (q,l) -> edge l, k = mt*16 + q*4 + j
            uf[0] = (short)f2bf(fmaxf(t0, 0.f));
            uf[1] = (short)f2bf(fmaxf(t1, 0.f));
            uf[2] = (short)f2bf(fmaxf(t2, 0.f));
            uf[3] = (short)f2bf(fmaxf(t3, 0.f));
            acc2 = __builtin_amdgcn_mfma_f32_16x16x16bf16_1k(we2f[mt], uf, acc2, 0, 0, 0);
        }
        // D: col=edge l, row=outcol q*4+r -> one 64B store per edge row (scatter via e)
        *(float4*)&outp[(size_t)e * DIM_A + q * 4] =
            make_float4(acc2[0] + be2v.x, acc2[1] + be2v.y,
                        acc2[2] + be2v.z, acc2[3] + be2v.w);
        pk = pk_n; ec = ec_n;
    }
}
#else
// Fallback (x32 MFMA + per-wave LDS round-trip), operand-swapped MFMA-2 + float4 store.
#define UPAD 268   // row stride 134 dwords (≡6 mod 32) — breaks the q-stride/l-stride alignment
__global__ __launch_bounds__(256) void k_edge(const u16* __restrict__ PQ,
                                              const float* __restrict__ attr,
                                              const int2* __restrict__ pack,
                                              const int2* __restrict__ eidx,
                                              const u16* __restrict__ Wct,
                                              const u16* __restrict__ We2t,
                                              const float* __restrict__ be2,
                                              float* __restrict__ outp) {
    __shared__ __align__(16) u16 ub[4][16][UPAD];
    const int tid = threadIdx.x, wid = tid >> 6, lane = tid & 63;
    const int q = lane >> 4, l = lane & 15;
    const float4 be2v = *(const float4*)&be2[q * 4];
    u16(*u)[UPAD] = ub[wid];

    s8 wcf[16];
#pragma unroll
    for (int mt = 0; mt < 16; mt++) {
        wcf[mt] = zero_s8();
        if (q < 2) wcf[mt] = *(const s8*)&Wct[(mt * 16 + l) * 16 + q * 8];
    }

    for (int tile = blockIdx.x * 4 + wid; tile < N_EDGES / 16; tile += gridDim.x * 4) {
        const int s = tile * 16 + l;
        const int2 pk = pack[s];
        const int2 ec = eidx[s];
        const int re = pk.x, e = ec.x, ce = ec.y;
        const u16* prow = PQ + (size_t)re * 512 + q * 4;
        const u16* qrow = PQ + (size_t)ce * 512 + 256 + q * 4;

        s8 af = zero_s8();
        if (q < 2) {
            const float* ap = &attr[(size_t)e * DIM_A + q * 8];
            float4 a0 = *(const float4*)ap;
            float4 a1 = *(const float4*)(ap + 4);
            af[0] = (short)f2bf(a0.x); af[1] = (short)f2bf(a0.y);
            af[2] = (short)f2bf(a0.z); af[3] = (short)f2bf(a0.w);
            af[4] = (short)f2bf(a1.x); af[5] = (short)f2bf(a1.y);
            af[6] = (short)f2bf(a1.z); af[7] = (short)f2bf(a1.w);
        }

#pragma unroll
        for (int mt = 0; mt < 16; mt++) {
            f4 cz = {0.f, 0.f, 0.f, 0.f};
            f4 acc = __builtin_amdgcn_mfma_f32_16x16x32_bf16(wcf[mt], af, cz, 0, 0, 0);
            ushort4 pu = *(const ushort4*)(prow + mt * 16);
            ushort4 qu = *(const ushort4*)(qrow + mt * 16);
            float t0 = bf2f(pu.x) + bf2f(qu.x) + acc[0];
            float t1 = bf2f(pu.y) + bf2f(qu.y) + acc[1];
            float t2 = bf2f(pu.z) + bf2f(qu.z) + acc[2];
            float t3 = bf2f(pu.w) + bf2f(qu.w) + acc[3];
            ushort4 o;
            o.x = f2bf(fmaxf(t0, 0.f)); o.y = f2bf(fmaxf(t1, 0.f));
            o.z = f2bf(fmaxf(t2, 0.f)); o.w = f2bf(fmaxf(t3, 0.f));
            *(ushort4*)&u[l][mt * 16 + q * 4] = o;
        }

        f4 acc2 = {0.f, 0.f, 0.f, 0.f};
#pragma unroll
        for (int ks = 0; ks < 8; ks++) {
            s8 uf = *(const s8*)&u[l][ks * 32 + q * 8];
            s8 wf = *(const s8*)&We2t[(size_t)l * DIM_H + ks * 32 + q * 8];
            acc2 = __builtin_amdgcn_mfma_f32_16x16x32_bf16(wf, uf, acc2, 0, 0, 0);
        }
        *(float4*)&outp[(size_t)e * DIM_A + q * 4] =
            make_float4(acc2[0] + be2v.x, acc2[1] + be2v.y,
                        acc2[2] + be2v.z, acc2[3] + be2v.w);
    }
}
#endif

extern "C" void kernel_launch(void* const* d_in, const int* in_sizes, int n_in,
                              void* d_out, int out_size, void* d_ws, size_t ws_size,
                              hipStream_t stream) {
    (void)in_sizes; (void)n_in; (void)out_size; (void)ws_size;
    const float* x    = (const float*)d_in[0];
    const int*   ei   = (const int*)d_in[1];
    const float* attr = (const float*)d_in[2];
    const float* W1   = (const float*)d_in[3];
    const float* b1   = (const float*)d_in[4];
    const float* W2   = (const float*)d_in[5];
    const float* b2   = (const float*)d_in[6];
    const float* Wo1  = (const float*)d_in[7];
    const float* bo1  = (const float*)d_in[8];
    const float* Wo2  = (const float*)d_in[9];
    const float* bo2  = (const float*)d_in[10];
    const float* We1  = (const float*)d_in[11];
    const float* be1  = (const float*)d_in[12];
    const float* We2  = (const float*)d_in[13];
    const float* be2  = (const float*)d_in[14];
    const int* rowi = ei;
    const int* coli = ei + N_EDGES;

    float* hout = (float*)d_out;                       // [N][128]
    float* eout = hout + (size_t)N_NODES * DIM_D;      // [E][16]

    char* ws = (char*)d_ws;
    size_t off = 0;
    auto nxt = [&](size_t b) -> void* {
        void* p = ws + off; off = (off + b + 255) & ~(size_t)255; return p;
    };
    float* dinv = (float*)nxt((size_t)N_NODES * 4);
    int* cnt    = (int*)nxt((size_t)N_NODES * 4);
    int* startp = (int*)nxt((size_t)(N_NODES + 1) * 4);
    int* cursor = (int*)nxt((size_t)N_NODES * 4);
    int2* pack  = (int2*)nxt((size_t)N_EDGES * 8);
    int2* eidx  = (int2*)nxt((size_t)N_EDGES * 8);
    u16* W1t   = (u16*)nxt(128 * 256 * 2);
    u16* W2t   = (u16*)nxt(128 * 256 * 2);
    u16* Wo1t  = (u16*)nxt(128 * 256 * 2);
    u16* Wo2t  = (u16*)nxt(128 * 256 * 2);
    u16* Wabt  = (u16*)nxt(512 * 128 * 2);   // [512][128]: Wa^T | Wb^T
    u16* Wct   = (u16*)nxt(256 * 16 * 2);
    u16* We2t  = (u16*)nxt(16 * 256 * 2);
    float* bpq = (float*)nxt(512 * 4);
    u16* xb    = (u16*)nxt((size_t)N_NODES * DIM_D * 2);     // x cast to bf16
    float* z   = (float*)nxt((size_t)N_NODES * DIM_D * 4);   // Âx / Ây accumulator (fp32)
    u16* h1    = (u16*)nxt((size_t)N_NODES * DIM_H * 2);     // intermediate [N][256]
    u16* yb    = (u16*)nxt((size_t)N_NODES * DIM_D * 2);
    // PQ [N][512] bf16 (51.2 MB) overlays z+h1 (both dead once hout is computed)
    u16* PQb = (u16*)z;

    const int gN = (N_NODES + 255) / 256;
    const int gE = (N_EDGES + 255) / 256;

    // weight transposes (bf16)
    k_twt<<<(128 * 256 + 255) / 256, 256, 0, stream>>>(W1, W1t, 128, 256);
    k_twt<<<(128 * 256 + 255) / 256, 256, 0, stream>>>(W2, W2t, 256, 128);
    k_twt<<<(128 * 256 + 255) / 256, 256, 0, stream>>>(Wo1, Wo1t, 128, 256);
    k_twt<<<(128 * 256 + 255) / 256, 256, 0, stream>>>(Wo2, Wo2t, 256, 128);
    k_twt<<<(128 * 256 + 255) / 256, 256, 0, stream>>>(We1, Wabt, 128, 256);
    k_twt<<<(128 * 256 + 255) / 256, 256, 0, stream>>>(We1 + 128 * 256, Wabt + 256 * 128, 128, 256);
    k_twt<<<(16 * 256 + 255) / 256, 256, 0, stream>>>(We1 + 256 * 256, Wct, 16, 256);
    k_twt<<<(16 * 256 + 255) / 256, 256, 0, stream>>>(We2, We2t, 256, 16);
    k_bpq<<<2, 256, 0, stream>>>(be1, bpq);

    // ---- CSR build (once; reused by both gather layers + edge predictor order) ----
    k_zero<<<gN, 256, 0, stream>>>(cnt);
    k_count<<<gE, 256, 0, stream>>>(coli, cnt);
    k_dinv<<<gN, 256, 0, stream>>>(cnt, dinv);
    k_scan<<<1, 1024, 0, stream>>>(cnt, startp);
    k_copy<<<gN, 256, 0, stream>>>(startp, cursor);
    k_fill<<<gE, 256, 0, stream>>>(rowi, coli, dinv, cursor, pack, eidx);

    // cast x -> bf16 (halves layer-1 gather traffic)
    k_cast<<<(N_NODES * DIM_D / 4 + 255) / 256, 256, 0, stream>>>(x, xb, N_NODES * DIM_D / 4);

    dim3 g4(391, 4), g2(391, 2), g8(391, 8);
    const int gG = (N_NODES + 3) / 4;   // 4 nodes (waves) per block
    // layer 1: z = Âx ; h1 = relu(z@W1 + b1)
    k_gather<<<gG, 256, 0, stream>>>(xb, pack, startp, dinv, z);
    k_gemm<false, false, true, true><<<g4, 256, 0, stream>>>(z, W1t, nullptr, b1, h1, N_NODES, 128, 256);
    // layer 2: y = h1@W2 ; z = Ây ; h2 = relu(z + b2) fused into next GEMM's A-stage
    k_gemm<true, false, false, true><<<g2, 256, 0, stream>>>(h1, W2t, nullptr, nullptr, yb, N_NODES, 256, 128);
    k_gather<<<gG, 256, 0, stream>>>(yb, pack, startp, dinv, z);
    // output MLP: h3 = relu(relu(z+b2)@Wo1 + bo1) ; h = h3@Wo2 + bo2 -> d_out (fp32)
    k_gemm<false, true, true, true><<<g4, 256, 0, stream>>>(z, Wo1t, b2, bo1, h1, N_NODES, 128, 256);
    k_gemm<true, false, false, false><<<g2, 256, 0, stream>>>(h1, Wo2t, nullptr, bo2, hout, N_NODES, 256, 128);
    // edge predictor precompute (single fused GEMM): PQ = [h@Wa + be1 | h@Wb]  (bf16, [N][512])
    k_gemm<false, false, false, true><<<g8, 256, 0, stream>>>(hout, Wabt, nullptr, bpq, PQb, N_NODES, 128, 512);
    // per-edge (CSR slot order): out = relu(P[src]+Q[dst]+attr@Wc)@We2 + be2
    k_edge<<<2048, 256, 0, stream>>>(PQb, attr, pack, eidx, Wct, We2t, be2, eout);
}

// Round 3
// 681.176 us; speedup vs baseline: 1.0693x; 1.0693x over previous
//
#include <hip/hip_runtime.h>
#include <hip/hip_bf16.h>

// Problem constants (from reference): N=50000, E=800000, D=128, H=256, A=16
#define N_NODES 50000
#define N_EDGES 800000
#define DIM_D   128
#define DIM_H   256
#define DIM_A   16

typedef unsigned short u16;
typedef __attribute__((ext_vector_type(4))) float f4;
typedef __attribute__((ext_vector_type(8))) short s8;
typedef __attribute__((ext_vector_type(4))) short s4;

__device__ __forceinline__ u16 f2bf(float f) {
    union { float f; unsigned u; } v; v.f = f;
    unsigned r = v.u + 0x7FFFu + ((v.u >> 16) & 1u);   // RNE
    return (u16)(r >> 16);
}
__device__ __forceinline__ float bf2f(u16 s) {
    union { unsigned u; float f; } v; v.u = ((unsigned)s) << 16; return v.f;
}
__device__ __forceinline__ s8 zero_s8() {
    s8 v;
#pragma unroll
    for (int i = 0; i < 8; i++) v[i] = 0;
    return v;
}

// ---- PQ permuted column layout (within each 64-col group of a PQ row) ----
// stored[i*32 + q*8 + s*4 + j] = logical[(2i+s)*16 + q*4 + j]
// => lane q reads ONE dwordx4 (16B) per (group,i) covering its chunks for mt'=2i and 2i+1.
__device__ __forceinline__ int pq_off(int mt, int q) {   // stored elem offset of logical chunk (mt, q)
    return (mt >> 2) * 64 + ((mt >> 1) & 1) * 32 + q * 8 + (mt & 1) * 4;
}

// ---------------- CSR build ----------------
__global__ __launch_bounds__(256) void k_zero(int* __restrict__ cnt) {
    int i = blockIdx.x * 256 + threadIdx.x;
    if (i < N_NODES) cnt[i] = 0;
}
__global__ __launch_bounds__(256) void k_count(const int* __restrict__ coli, int* __restrict__ cnt) {
    int e = blockIdx.x * 256 + threadIdx.x;
    if (e < N_EDGES) atomicAdd(&cnt[coli[e]], 1);
}
__global__ __launch_bounds__(256) void k_dinv(const int* __restrict__ cnt, float* __restrict__ dinv) {
    int i = blockIdx.x * 256 + threadIdx.x;
    if (i < N_NODES) dinv[i] = rsqrtf((float)(cnt[i] + 1));   // +1 self-loop
}

#define SCAN_C 49   // 1024 * 49 = 50176 >= N_NODES
__global__ __launch_bounds__(1024) void k_scan(const int* __restrict__ cnt, int* __restrict__ start) {
    __shared__ int ps[1024];
    int t = threadIdx.x;
    int base = t * SCAN_C;
    int sum = 0;
    for (int i = 0; i < SCAN_C; i++) {
        int idx = base + i;
        sum += (idx < N_NODES) ? cnt[idx] : 0;
    }
    ps[t] = sum;
    __syncthreads();
    for (int ofs = 1; ofs < 1024; ofs <<= 1) {
        int v = (t >= ofs) ? ps[t - ofs] : 0;
        __syncthreads();
        ps[t] += v;
        __syncthreads();
    }
    int run = (t > 0) ? ps[t - 1] : 0;
    for (int i = 0; i < SCAN_C; i++) {
        int idx = base + i;
        if (idx < N_NODES) {
            start[idx] = run;
            run += cnt[idx];
        }
    }
    if (t == 1023) start[N_NODES] = ps[1023];
}
__global__ __launch_bounds__(256) void k_copy(const int* __restrict__ start, int* __restrict__ cursor) {
    int i = blockIdx.x * 256 + threadIdx.x;
    if (i < N_NODES) cursor[i] = start[i];
}
// pack[slot] = {src_node, dinv[src]*dinv[dst]} bucketed by destination
// eidx[slot] = {orig_edge, dst_node} (for CSR-ordered edge predictor)
__global__ __launch_bounds__(256) void k_fill(const int* __restrict__ rowi, const int* __restrict__ coli,
                                              const float* __restrict__ dinv,
                                              int* __restrict__ cursor, int2* __restrict__ pack,
                                              int2* __restrict__ eidx) {
    int e = blockIdx.x * 256 + threadIdx.x;
    if (e >= N_EDGES) return;
    int r = rowi[e], c = coli[e];
    int slot = atomicAdd(&cursor[c], 1);
    float w = dinv[r] * dinv[c];
    pack[slot] = make_int2(r, __float_as_int(w));
    eidx[slot] = make_int2(e, c);
}

// ---------------- fp32 -> bf16 cast (x table) ----------------
__global__ __launch_bounds__(256) void k_cast(const float* __restrict__ X, u16* __restrict__ Y, int n4) {
    int i = blockIdx.x * 256 + threadIdx.x;
    if (i >= n4) return;
    float4 v = *(const float4*)&X[(size_t)i * 4];
    ushort4 o;
    o.x = f2bf(v.x); o.y = f2bf(v.y); o.z = f2bf(v.z); o.w = f2bf(v.w);
    *(ushort4*)&Y[(size_t)i * 4] = o;
}

// ---------------- CSR gather: z[n] = X[n]*dinv[n]^2 + sum_{e->n} X[src]*w ----------------
// one wave per node; two 32-lane halves process alternate CSR entries, lane covers 4 cols (bf16 X)
__global__ __launch_bounds__(256) void k_gather(const u16* __restrict__ X,
                                                const int2* __restrict__ pack,
                                                const int* __restrict__ start,
                                                const float* __restrict__ dinv,
                                                float* __restrict__ z) {
    int node = blockIdx.x * 4 + (threadIdx.x >> 6);
    if (node >= N_NODES) return;
    int lane = threadIdx.x & 63;
    int half = lane >> 5, j = lane & 31;
    int c4 = j * 4;
    float di = dinv[node];
    f4 acc = {0.f, 0.f, 0.f, 0.f};
    if (half == 0) {
        float sl = di * di;
        ushort4 u = *(const ushort4*)&X[(size_t)node * DIM_D + c4];
        acc[0] = bf2f(u.x) * sl; acc[1] = bf2f(u.y) * sl;
        acc[2] = bf2f(u.z) * sl; acc[3] = bf2f(u.w) * sl;
    }
    int s = start[node], e = start[node + 1];
#pragma unroll 8
    for (int i = s + half; i < e; i += 2) {
        int2 p = pack[i];
        float w = __int_as_float(p.y);
        ushort4 u = *(const ushort4*)&X[(size_t)p.x * DIM_D + c4];
        acc[0] += bf2f(u.x) * w; acc[1] += bf2f(u.y) * w;
        acc[2] += bf2f(u.z) * w; acc[3] += bf2f(u.w) * w;
    }
    // combine halves: lane j (<32) += lane j+32
    float t0 = acc[0] + __shfl(acc[0], j + 32);
    float t1 = acc[1] + __shfl(acc[1], j + 32);
    float t2 = acc[2] + __shfl(acc[2], j + 32);
    float t3 = acc[3] + __shfl(acc[3], j + 32);
    if (half == 0)
        *(float4*)&z[(size_t)node * DIM_D + c4] = make_float4(t0, t1, t2, t3);
}

// ---------------- weight transpose+cast: W[K][Nn] fp32 -> Wt[Nn][K] bf16 ----------------
__global__ __launch_bounds__(256) void k_twt(const float* __restrict__ W, u16* __restrict__ Wt,
                                             int K, int Nn) {
    int idx = blockIdx.x * 256 + threadIdx.x;
    if (idx >= K * Nn) return;
    int k = idx / Nn, n = idx - k * Nn;
    Wt[n * K + k] = f2bf(W[idx]);
}

// combined edge-predictor bias: bpq[0..255]=be1, bpq[256..511]=0
__global__ __launch_bounds__(256) void k_bpq(const float* __restrict__ be1, float* __restrict__ bpq) {
    int i = blockIdx.x * 256 + threadIdx.x;
    if (i < 512) bpq[i] = (i < 256) ? be1[i] : 0.f;
}

// ---------------- MFMA GEMM: C[M][Nn] = post(A[M][K] @ W + postB), W given as Wt[Nn][K] bf16 ----
// A_BF16: A is bf16[M][K] else fp32. PRE_BR: A' = relu(A + preB[k]) before cast.
// PERM_PQ: store columns permuted per 64-col group (pq layout for k_edge wide loads).
#define BM 128
#define BN 64
#define BK 32
#define BKP 56   // padded K stride in LDS (bf16 elems)

template <bool A_BF16, bool PRE_BR, bool POST_RELU, bool OUT_BF16, bool PERM_PQ>
__global__ __launch_bounds__(256) void k_gemm(const void* __restrict__ Ap,
                                              const u16* __restrict__ Wt,
                                              const float* __restrict__ preB,
                                              const float* __restrict__ postB,
                                              void* __restrict__ Cp,
                                              int M, int K, int Nn) {
    __shared__ __align__(16) u16 As[BM * BKP];
    __shared__ __align__(16) u16 Bs[BN * BKP];
    const int tid = threadIdx.x;
    const int wid = tid >> 6, lane = tid & 63;
    const int q = lane >> 4, l = lane & 15;
    const int bm = blockIdx.x * BM, bn = blockIdx.y * BN;

    f4 acc[8];
#pragma unroll
    for (int i = 0; i < 8; i++) { f4 zz = {0.f, 0.f, 0.f, 0.f}; acc[i] = zz; }

    for (int k0 = 0; k0 < K; k0 += BK) {
        __syncthreads();
        // stage W tile: Bs[n][k], n in [bn,bn+64), k in [k0,k0+32)
        {
            int n = tid >> 2, kc = (tid & 3) * 8;
            *(int4*)&Bs[n * BKP + kc] = *(const int4*)&Wt[(size_t)(bn + n) * K + k0 + kc];
        }
        // stage A tile: As[m][k]
        if (A_BF16) {
            const u16* A = (const u16*)Ap;
#pragma unroll
            for (int p = 0; p < 2; p++) {
                int m = (tid >> 2) + p * 64, kc = (tid & 3) * 8;
                int gm = bm + m; if (gm >= M) gm = M - 1;
                *(int4*)&As[m * BKP + kc] = *(const int4*)&A[(size_t)gm * K + k0 + kc];
            }
        } else {
            const float* A = (const float*)Ap;
#pragma unroll
            for (int p = 0; p < 4; p++) {
                int m = (tid >> 3) + p * 32, k4 = (tid & 7) * 4;
                int gm = bm + m; if (gm >= M) gm = M - 1;
                float4 v = *(const float4*)&A[(size_t)gm * K + k0 + k4];
                if (PRE_BR) {
                    const float4 pb = *(const float4*)&preB[k0 + k4];
                    v.x = fmaxf(v.x + pb.x, 0.f);
                    v.y = fmaxf(v.y + pb.y, 0.f);
                    v.z = fmaxf(v.z + pb.z, 0.f);
                    v.w = fmaxf(v.w + pb.w, 0.f);
                }
                ushort4 o;
                o.x = f2bf(v.x); o.y = f2bf(v.y); o.z = f2bf(v.z); o.w = f2bf(v.w);
                *(ushort4*)&As[m * BKP + k4] = o;
            }
        }
        __syncthreads();

        s8 af[2], bf[4];
#pragma unroll
        for (int mt = 0; mt < 2; mt++)
            af[mt] = *(const s8*)&As[(wid * 32 + mt * 16 + l) * BKP + q * 8];
#pragma unroll
        for (int nt = 0; nt < 4; nt++)
            bf[nt] = *(const s8*)&Bs[(nt * 16 + l) * BKP + q * 8];
#pragma unroll
        for (int mt = 0; mt < 2; mt++)
#pragma unroll
            for (int nt = 0; nt < 4; nt++)
                acc[mt * 4 + nt] = __builtin_amdgcn_mfma_f32_16x16x32_bf16(
                    af[mt], bf[nt], acc[mt * 4 + nt], 0, 0, 0);
    }

    // epilogue: C row = q*4+r, col = l (per 16x16 tile)
#pragma unroll
    for (int mt = 0; mt < 2; mt++) {
#pragma unroll
        for (int nt = 0; nt < 4; nt++) {
            int colg = bn + nt * 16 + l;                // logical col (bias index)
            float pb = postB ? postB[colg] : 0.0f;
            int cols = colg;
            if (PERM_PQ) {
                int w = colg & 63, mtL = w >> 4;
                cols = (colg & ~63) | (((mtL >> 1) & 1) * 32) | (((w >> 2) & 3) * 8)
                       | ((mtL & 1) * 4) | (w & 3);
            }
#pragma unroll
            for (int r = 0; r < 4; r++) {
                int rowg = bm + wid * 32 + mt * 16 + q * 4 + r;
                if (rowg < M) {
                    float v = acc[mt * 4 + nt][r] + pb;
                    if (POST_RELU) v = fmaxf(v, 0.f);
                    if (OUT_BF16)
                        ((u16*)Cp)[(size_t)rowg * Nn + cols] = f2bf(v);
                    else
                        ((float*)Cp)[(size_t)rowg * Nn + cols] = v;
                }
            }
        }
    }
}

// ---------------- edge predictor: 16 edges (CSR slots) per wave -----------------------------
// CSR-ordered (Q gathers hit same lines across lanes). v4:
//  * PQ stored in permuted layout -> P/Q row read as 8 dwordx4 loads (was 16 dwordx2):
//    VMEM instrs/tile 35 -> 20, line-subrequests halved (4 q-lanes = one 64B chunk per edge)
//  * asm value-keeps pin the whole gather batch above the math (round-2 lesson: sched_barrier
//    alone doesn't stop IR-level load sinking -> VGPR stayed 80, zero MLP gain)
//  * next tile's pack/eidx prefetched before compute
#if __has_builtin(__builtin_amdgcn_mfma_f32_16x16x16bf16_1k)
#define KEEP4(a,b,c,d) asm volatile("" :: "v"(a), "v"(b), "v"(c), "v"(d))
__global__ __launch_bounds__(256) void k_edge(const u16* __restrict__ PQ,     // [N][512]: P|Q (permuted)
                                              const float* __restrict__ attr,
                                              const int2* __restrict__ pack,
                                              const int2* __restrict__ eidx,
                                              const u16* __restrict__ Wct,    // [256][16] bf16
                                              const u16* __restrict__ We2t,   // [16][256] bf16
                                              const float* __restrict__ be2,
                                              float* __restrict__ outp) {
    const int tid = threadIdx.x, wid = tid >> 6, lane = tid & 63;
    const int q = lane >> 4, l = lane & 15;
    const float4 be2v = *(const float4*)&be2[q * 4];
    const int NT = N_EDGES / 16;
    const int step = gridDim.x * 4;

    // tile-invariant fragments in registers: We2^T A-frags + Wc^T A-frags (logical layout)
    s4 we2f[16], wcf[16];
#pragma unroll
    for (int mt = 0; mt < 16; mt++) {
        we2f[mt] = *(const s4*)&We2t[(size_t)l * DIM_H + mt * 16 + q * 4];
        wcf[mt]  = *(const s4*)&Wct[(mt * 16 + l) * 16 + q * 4];
    }

    int tile = blockIdx.x * 4 + wid;
    if (tile >= NT) return;
    int2 pk = pack[tile * 16 + l];        // {src, weight(unused)}
    int2 ec = eidx[tile * 16 + l];        // {orig edge, dst}

    for (; tile < NT; tile += step) {
        const int re = pk.x, e = ec.x, ce = ec.y;
        const u16* prow = PQ + (size_t)re * 512 + q * 8;          // P half (random, LLC)
        const u16* qrow = PQ + (size_t)ce * 512 + 256 + q * 8;    // Q half (CSR runs, L1)

        // issue the whole gather batch: attr + 16 wide P/Q loads (16B/lane, 64B/edge/instr)
        float4 av = *(const float4*)&attr[(size_t)e * DIM_A + q * 4];
        s8 pw[8], qw[8];
#pragma unroll
        for (int w = 0; w < 8; w++) {
            pw[w] = *(const s8*)(prow + w * 32);
            qw[w] = *(const s8*)(qrow + w * 32);
        }
        // prefetch next tile's indices (independent of current compute)
        int ntile = tile + step;
        int ns = (ntile < NT) ? ntile * 16 + l : l;
        int2 pk_n = pack[ns];
        int2 ec_n = eidx[ns];
        // pin: force all batch results live here (IR sinking cannot cross asm operands)
        KEEP4(pw[0], pw[1], pw[2], pw[3]);
        KEEP4(pw[4], pw[5], pw[6], pw[7]);
        KEEP4(qw[0], qw[1], qw[2], qw[3]);
        KEEP4(qw[4], qw[5], qw[6], qw[7]);
        __builtin_amdgcn_sched_barrier(0);

        s4 af;   // attr B-frag: B[k=q*4+j][n=edge=l]
        af[0] = (short)f2bf(av.x); af[1] = (short)f2bf(av.y);
        af[2] = (short)f2bf(av.z); af[3] = (short)f2bf(av.w);

        f4 acc2 = {0.f, 0.f, 0.f, 0.f};
#pragma unroll
        for (int w = 0; w < 8; w++) {
#pragma unroll
            for (int s = 0; s < 2; s++) {
                const int mt = w * 2 + s;
                f4 cz = {0.f, 0.f, 0.f, 0.f};
                f4 acc = __builtin_amdgcn_mfma_f32_16x16x16bf16_1k(wcf[mt], af, cz, 0, 0, 0);
                float t0 = bf2f((u16)pw[w][s * 4 + 0]) + bf2f((u16)qw[w][s * 4 + 0]) + acc[0];
                float t1 = bf2f((u16)pw[w][s * 4 + 1]) + bf2f((u16)qw[w][s * 4 + 1]) + acc[1];
                float t2 = bf2f((u16)pw[w][s * 4 + 2]) + bf2f((u16)qw[w][s * 4 + 2]) + acc[2];
                float t3 = bf2f((u16)pw[w][s * 4 + 3]) + bf2f((u16)qw[w][s * 4 + 3]) + acc[3];
                s4 uf;   // B-frag of u^T: lane (q,l) -> edge l, k = mt*16 + q*4 + j
                uf[0] = (short)f2bf(fmaxf(t0, 0.f));
                uf[1] = (short)f2bf(fmaxf(t1, 0.f));
                uf[2] = (short)f2bf(fmaxf(t2, 0.f));
                uf[3] = (short)f2bf(fmaxf(t3, 0.f));
                acc2 = __builtin_amdgcn_mfma_f32_16x16x16bf16_1k(we2f[mt], uf, acc2, 0, 0, 0);
            }
        }
        // D: col=edge l, row=outcol q*4+r -> one 64B store per edge row (scatter via e)
        *(float4*)&outp[(size_t)e * DIM_A + q * 4] =
            make_float4(acc2[0] + be2v.x, acc2[1] + be2v.y,
                        acc2[2] + be2v.z, acc2[3] + be2v.w);
        pk = pk_n; ec = ec_n;
    }
}
#else
// Fallback (x32 MFMA + per-wave LDS round-trip), operand-swapped MFMA-2 + float4 store.
// NOTE: consumes the SAME permuted PQ layout via pq_off(mt,q).
#define UPAD 268   // row stride 134 dwords (≡6 mod 32) — breaks the q-stride/l-stride alignment
__global__ __launch_bounds__(256) void k_edge(const u16* __restrict__ PQ,
                                              const float* __restrict__ attr,
                                              const int2* __restrict__ pack,
                                              const int2* __restrict__ eidx,
                                              const u16* __restrict__ Wct,
                                              const u16* __restrict__ We2t,
                                              const float* __restrict__ be2,
                                              float* __restrict__ outp) {
    __shared__ __align__(16) u16 ub[4][16][UPAD];
    const int tid = threadIdx.x, wid = tid >> 6, lane = tid & 63;
    const int q = lane >> 4, l = lane & 15;
    const float4 be2v = *(const float4*)&be2[q * 4];
    u16(*u)[UPAD] = ub[wid];

    s8 wcf[16];
#pragma unroll
    for (int mt = 0; mt < 16; mt++) {
        wcf[mt] = zero_s8();
        if (q < 2) wcf[mt] = *(const s8*)&Wct[(mt * 16 + l) * 16 + q * 8];
    }

    for (int tile = blockIdx.x * 4 + wid; tile < N_EDGES / 16; tile += gridDim.x * 4) {
        const int s = tile * 16 + l;
        const int2 pk = pack[s];
        const int2 ec = eidx[s];
        const int re = pk.x, e = ec.x, ce = ec.y;
        const u16* prow = PQ + (size_t)re * 512;
        const u16* qrow = PQ + (size_t)ce * 512 + 256;

        s8 af = zero_s8();
        if (q < 2) {
            const float* ap = &attr[(size_t)e * DIM_A + q * 8];
            float4 a0 = *(const float4*)ap;
            float4 a1 = *(const float4*)(ap + 4);
            af[0] = (short)f2bf(a0.x); af[1] = (short)f2bf(a0.y);
            af[2] = (short)f2bf(a0.z); af[3] = (short)f2bf(a0.w);
            af[4] = (short)f2bf(a1.x); af[5] = (short)f2bf(a1.y);
            af[6] = (short)f2bf(a1.z); af[7] = (short)f2bf(a1.w);
        }

#pragma unroll
        for (int mt = 0; mt < 16; mt++) {
            f4 cz = {0.f, 0.f, 0.f, 0.f};
            f4 acc = __builtin_amdgcn_mfma_f32_16x16x32_bf16(wcf[mt], af, cz, 0, 0, 0);
            ushort4 pu = *(const ushort4*)(prow + pq_off(mt, q));
            ushort4 qu = *(const ushort4*)(qrow + pq_off(mt, q));
            float t0 = bf2f(pu.x) + bf2f(qu.x) + acc[0];
            float t1 = bf2f(pu.y) + bf2f(qu.y) + acc[1];
            float t2 = bf2f(pu.z) + bf2f(qu.z) + acc[2];
            float t3 = bf2f(pu.w) + bf2f(qu.w) + acc[3];
            ushort4 o;
            o.x = f2bf(fmaxf(t0, 0.f)); o.y = f2bf(fmaxf(t1, 0.f));
            o.z = f2bf(fmaxf(t2, 0.f)); o.w = f2bf(fmaxf(t3, 0.f));
            *(ushort4*)&u[l][mt * 16 + q * 4] = o;
        }

        f4 acc2 = {0.f, 0.f, 0.f, 0.f};
#pragma unroll
        for (int ks = 0; ks < 8; ks++) {
            s8 uf = *(const s8*)&u[l][ks * 32 + q * 8];
            s8 wf = *(const s8*)&We2t[(size_t)l * DIM_H + ks * 32 + q * 8];
            acc2 = __builtin_amdgcn_mfma_f32_16x16x32_bf16(wf, uf, acc2, 0, 0, 0);
        }
        *(float4*)&outp[(size_t)e * DIM_A + q * 4] =
            make_float4(acc2[0] + be2v.x, acc2[1] + be2v.y,
                        acc2[2] + be2v.z, acc2[3] + be2v.w);
    }
}
#endif

extern "C" void kernel_launch(void* const* d_in, const int* in_sizes, int n_in,
                              void* d_out, int out_size, void* d_ws, size_t ws_size,
                              hipStream_t stream) {
    (void)in_sizes; (void)n_in; (void)out_size; (void)ws_size;
    const float* x    = (const float*)d_in[0];
    const int*   ei   = (const int*)d_in[1];
    const float* attr = (const float*)d_in[2];
    const float* W1   = (const float*)d_in[3];
    const float* b1   = (const float*)d_in[4];
    const float* W2   = (const float*)d_in[5];
    const float* b2   = (const float*)d_in[6];
    const float* Wo1  = (const float*)d_in[7];
    const float* bo1  = (const float*)d_in[8];
    const float* Wo2  = (const float*)d_in[9];
    const float* bo2  = (const float*)d_in[10];
    const float* We1  = (const float*)d_in[11];
    const float* be1  = (const float*)d_in[12];
    const float* We2  = (const float*)d_in[13];
    const float* be2  = (const float*)d_in[14];
    const int* rowi = ei;
    const int* coli = ei + N_EDGES;

    float* hout = (float*)d_out;                       // [N][128]
    float* eout = hout + (size_t)N_NODES * DIM_D;      // [E][16]

    char* ws = (char*)d_ws;
    size_t off = 0;
    auto nxt = [&](size_t b) -> void* {
        void* p = ws + off; off = (off + b + 255) & ~(size_t)255; return p;
    };
    float* dinv = (float*)nxt((size_t)N_NODES * 4);
    int* cnt    = (int*)nxt((size_t)N_NODES * 4);
    int* startp = (int*)nxt((size_t)(N_NODES + 1) * 4);
    int* cursor = (int*)nxt((size_t)N_NODES * 4);
    int2* pack  = (int2*)nxt((size_t)N_EDGES * 8);
    int2* eidx  = (int2*)nxt((size_t)N_EDGES * 8);
    u16* W1t   = (u16*)nxt(128 * 256 * 2);
    u16* W2t   = (u16*)nxt(128 * 256 * 2);
    u16* Wo1t  = (u16*)nxt(128 * 256 * 2);
    u16* Wo2t  = (u16*)nxt(128 * 256 * 2);
    u16* Wabt  = (u16*)nxt(512 * 128 * 2);   // [512][128]: Wa^T | Wb^T
    u16* Wct   = (u16*)nxt(256 * 16 * 2);
    u16* We2t  = (u16*)nxt(16 * 256 * 2);
    float* bpq = (float*)nxt(512 * 4);
    u16* xb    = (u16*)nxt((size_t)N_NODES * DIM_D * 2);     // x cast to bf16
    float* z   = (float*)nxt((size_t)N_NODES * DIM_D * 4);   // Âx / Ây accumulator (fp32)
    u16* h1    = (u16*)nxt((size_t)N_NODES * DIM_H * 2);     // intermediate [N][256]
    u16* yb    = (u16*)nxt((size_t)N_NODES * DIM_D * 2);
    // PQ [N][512] bf16 (51.2 MB) overlays z+h1 (both dead once hout is computed)
    u16* PQb = (u16*)z;

    const int gN = (N_NODES + 255) / 256;
    const int gE = (N_EDGES + 255) / 256;

    // weight transposes (bf16)
    k_twt<<<(128 * 256 + 255) / 256, 256, 0, stream>>>(W1, W1t, 128, 256);
    k_twt<<<(128 * 256 + 255) / 256, 256, 0, stream>>>(W2, W2t, 256, 128);
    k_twt<<<(128 * 256 + 255) / 256, 256, 0, stream>>>(Wo1, Wo1t, 128, 256);
    k_twt<<<(128 * 256 + 255) / 256, 256, 0, stream>>>(Wo2, Wo2t, 256, 128);
    k_twt<<<(128 * 256 + 255) / 256, 256, 0, stream>>>(We1, Wabt, 128, 256);
    k_twt<<<(128 * 256 + 255) / 256, 256, 0, stream>>>(We1 + 128 * 256, Wabt + 256 * 128, 128, 256);
    k_twt<<<(16 * 256 + 255) / 256, 256, 0, stream>>>(We1 + 256 * 256, Wct, 16, 256);
    k_twt<<<(16 * 256 + 255) / 256, 256, 0, stream>>>(We2, We2t, 256, 16);
    k_bpq<<<2, 256, 0, stream>>>(be1, bpq);

    // ---- CSR build (once; reused by both gather layers + edge predictor order) ----
    k_zero<<<gN, 256, 0, stream>>>(cnt);
    k_count<<<gE, 256, 0, stream>>>(coli, cnt);
    k_dinv<<<gN, 256, 0, stream>>>(cnt, dinv);
    k_scan<<<1, 1024, 0, stream>>>(cnt, startp);
    k_copy<<<gN, 256, 0, stream>>>(startp, cursor);
    k_fill<<<gE, 256, 0, stream>>>(rowi, coli, dinv, cursor, pack, eidx);

    // cast x -> bf16 (halves layer-1 gather traffic)
    k_cast<<<(N_NODES * DIM_D / 4 + 255) / 256, 256, 0, stream>>>(x, xb, N_NODES * DIM_D / 4);

    dim3 g4(391, 4), g2(391, 2), g8(391, 8);
    const int gG = (N_NODES + 3) / 4;   // 4 nodes (waves) per block
    // layer 1: z = Âx ; h1 = relu(z@W1 + b1)
    k_gather<<<gG, 256, 0, stream>>>(xb, pack, startp, dinv, z);
    k_gemm<false, false, true, true, false><<<g4, 256, 0, stream>>>(z, W1t, nullptr, b1, h1, N_NODES, 128, 256);
    // layer 2: y = h1@W2 ; z = Ây ; h2 = relu(z + b2) fused into next GEMM's A-stage
    k_gemm<true, false, false, true, false><<<g2, 256, 0, stream>>>(h1, W2t, nullptr, nullptr, yb, N_NODES, 256, 128);
    k_gather<<<gG, 256, 0, stream>>>(yb, pack, startp, dinv, z);
    // output MLP: h3 = relu(relu(z+b2)@Wo1 + bo1) ; h = h3@Wo2 + bo2 -> d_out (fp32)
    k_gemm<false, true, true, true, false><<<g4, 256, 0, stream>>>(z, Wo1t, b2, bo1, h1, N_NODES, 128, 256);
    k_gemm<true, false, false, false, false><<<g2, 256, 0, stream>>>(h1, Wo2t, nullptr, bo2, hout, N_NODES, 256, 128);
    // edge predictor precompute (single fused GEMM): PQ = [h@Wa + be1 | h@Wb]  (bf16, [N][512], permuted cols)
    k_gemm<false, false, false, true, true><<<g8, 256, 0, stream>>>(hout, Wabt, nullptr, bpq, PQb, N_NODES, 128, 512);
    // per-edge (CSR slot order): out = relu(P[src]+Q[dst]+attr@Wc)@We2 + be2
    k_edge<<<2048, 256, 0, stream>>>(PQb, attr, pack, eidx, Wct, We2t, be2, eout);
}

// Round 5
// 667.113 us; speedup vs baseline: 1.0918x; 1.0211x over previous
//
#include <hip/hip_runtime.h>
#include <hip/hip_bf16.h>

// Problem constants (from reference): N=50000, E=800000, D=128, H=256, A=16
#define N_NODES 50000
#define N_EDGES 800000
#define DIM_D   128
#define DIM_H   256
#define DIM_A   16

typedef unsigned short u16;
typedef __attribute__((ext_vector_type(4))) float f4;
typedef __attribute__((ext_vector_type(8))) short s8;
typedef __attribute__((ext_vector_type(4))) short s4;

__device__ __forceinline__ u16 f2bf(float f) {
    union { float f; unsigned u; } v; v.f = f;
    unsigned r = v.u + 0x7FFFu + ((v.u >> 16) & 1u);   // RNE
    return (u16)(r >> 16);
}
__device__ __forceinline__ float bf2f(u16 s) {
    union { unsigned u; float f; } v; v.u = ((unsigned)s) << 16; return v.f;
}
__device__ __forceinline__ s8 zero_s8() {
    s8 v;
#pragma unroll
    for (int i = 0; i < 8; i++) v[i] = 0;
    return v;
}

// ---- PQ permuted column layout (within each 64-col group of a PQ row) ----
// stored[i*32 + q*8 + s*4 + j] = logical[(2i+s)*16 + q*4 + j]
// => lane q reads ONE dwordx4 (16B) per (group,i) covering its chunks for mt'=2i and 2i+1.
__device__ __forceinline__ int pq_off(int mt, int q) {   // stored elem offset of logical chunk (mt, q)
    return (mt >> 2) * 64 + ((mt >> 1) & 1) * 32 + q * 8 + (mt & 1) * 4;
}

// ---------------- CSR build ----------------
__global__ __launch_bounds__(256) void k_zero(int* __restrict__ cnt) {
    int i = blockIdx.x * 256 + threadIdx.x;
    if (i < N_NODES) cnt[i] = 0;
}
__global__ __launch_bounds__(256) void k_count(const int* __restrict__ coli, int* __restrict__ cnt) {
    int e = blockIdx.x * 256 + threadIdx.x;
    if (e < N_EDGES) atomicAdd(&cnt[coli[e]], 1);
}
__global__ __launch_bounds__(256) void k_dinv(const int* __restrict__ cnt, float* __restrict__ dinv) {
    int i = blockIdx.x * 256 + threadIdx.x;
    if (i < N_NODES) dinv[i] = rsqrtf((float)(cnt[i] + 1));   // +1 self-loop
}

#define SCAN_C 49   // 1024 * 49 = 50176 >= N_NODES
__global__ __launch_bounds__(1024) void k_scan(const int* __restrict__ cnt, int* __restrict__ start) {
    __shared__ int ps[1024];
    int t = threadIdx.x;
    int base = t * SCAN_C;
    int sum = 0;
    for (int i = 0; i < SCAN_C; i++) {
        int idx = base + i;
        sum += (idx < N_NODES) ? cnt[idx] : 0;
    }
    ps[t] = sum;
    __syncthreads();
    for (int ofs = 1; ofs < 1024; ofs <<= 1) {
        int v = (t >= ofs) ? ps[t - ofs] : 0;
        __syncthreads();
        ps[t] += v;
        __syncthreads();
    }
    int run = (t > 0) ? ps[t - 1] : 0;
    for (int i = 0; i < SCAN_C; i++) {
        int idx = base + i;
        if (idx < N_NODES) {
            start[idx] = run;
            run += cnt[idx];
        }
    }
    if (t == 1023) start[N_NODES] = ps[1023];
}
__global__ __launch_bounds__(256) void k_copy(const int* __restrict__ start, int* __restrict__ cursor) {
    int i = blockIdx.x * 256 + threadIdx.x;
    if (i < N_NODES) cursor[i] = start[i];
}
// pack[slot] = {src_node, dinv[src]*dinv[dst]} bucketed by destination
// eidx[slot] = {orig_edge, dst_node} (for CSR-ordered edge predictor)
__global__ __launch_bounds__(256) void k_fill(const int* __restrict__ rowi, const int* __restrict__ coli,
                                              const float* __restrict__ dinv,
                                              int* __restrict__ cursor, int2* __restrict__ pack,
                                              int2* __restrict__ eidx) {
    int e = blockIdx.x * 256 + threadIdx.x;
    if (e >= N_EDGES) return;
    int r = rowi[e], c = coli[e];
    int slot = atomicAdd(&cursor[c], 1);
    float w = dinv[r] * dinv[c];
    pack[slot] = make_int2(r, __float_as_int(w));
    eidx[slot] = make_int2(e, c);
}

// ---------------- fp32 -> bf16 cast (x table) ----------------
__global__ __launch_bounds__(256) void k_cast(const float* __restrict__ X, u16* __restrict__ Y, int n4) {
    int i = blockIdx.x * 256 + threadIdx.x;
    if (i >= n4) return;
    float4 v = *(const float4*)&X[(size_t)i * 4];
    ushort4 o;
    o.x = f2bf(v.x); o.y = f2bf(v.y); o.z = f2bf(v.z); o.w = f2bf(v.w);
    *(ushort4*)&Y[(size_t)i * 4] = o;
}

// ---------------- CSR gather: z[n] = X[n]*dinv[n]^2 + sum_{e->n} X[src]*w ----------------
// one wave per node; two 32-lane halves take contiguous sub-ranges of the CSR span
// (contiguous => 4-deep independent load batches), lane covers 4 cols (bf16 X)
__global__ __launch_bounds__(256) void k_gather(const u16* __restrict__ X,
                                                const int2* __restrict__ pack,
                                                const int* __restrict__ start,
                                                const float* __restrict__ dinv,
                                                float* __restrict__ z) {
    int node = blockIdx.x * 4 + (threadIdx.x >> 6);
    if (node >= N_NODES) return;
    int lane = threadIdx.x & 63;
    int half = lane >> 5, j = lane & 31;
    int c4 = j * 4;
    float di = dinv[node];
    f4 acc = {0.f, 0.f, 0.f, 0.f};
    if (half == 0) {
        float sl = di * di;
        ushort4 u = *(const ushort4*)&X[(size_t)node * DIM_D + c4];
        acc[0] = bf2f(u.x) * sl; acc[1] = bf2f(u.y) * sl;
        acc[2] = bf2f(u.z) * sl; acc[3] = bf2f(u.w) * sl;
    }
    int s0 = start[node], e0 = start[node + 1];
    int h0 = (e0 - s0 + 1) >> 1;
    int i   = half ? (s0 + h0) : s0;
    int end = half ? e0 : (s0 + h0);
    // 4-deep software pipeline: 4 independent pack loads, then 4 row loads in flight
    for (; i + 3 < end; i += 4) {
        int2 p0 = pack[i], p1 = pack[i + 1], p2 = pack[i + 2], p3 = pack[i + 3];
        ushort4 u0 = *(const ushort4*)&X[(size_t)p0.x * DIM_D + c4];
        ushort4 u1 = *(const ushort4*)&X[(size_t)p1.x * DIM_D + c4];
        ushort4 u2 = *(const ushort4*)&X[(size_t)p2.x * DIM_D + c4];
        ushort4 u3 = *(const ushort4*)&X[(size_t)p3.x * DIM_D + c4];
        float w0 = __int_as_float(p0.y), w1 = __int_as_float(p1.y);
        float w2 = __int_as_float(p2.y), w3 = __int_as_float(p3.y);
        acc[0] += bf2f(u0.x) * w0; acc[1] += bf2f(u0.y) * w0;
        acc[2] += bf2f(u0.z) * w0; acc[3] += bf2f(u0.w) * w0;
        acc[0] += bf2f(u1.x) * w1; acc[1] += bf2f(u1.y) * w1;
        acc[2] += bf2f(u1.z) * w1; acc[3] += bf2f(u1.w) * w1;
        acc[0] += bf2f(u2.x) * w2; acc[1] += bf2f(u2.y) * w2;
        acc[2] += bf2f(u2.z) * w2; acc[3] += bf2f(u2.w) * w2;
        acc[0] += bf2f(u3.x) * w3; acc[1] += bf2f(u3.y) * w3;
        acc[2] += bf2f(u3.z) * w3; acc[3] += bf2f(u3.w) * w3;
    }
    for (; i < end; i++) {
        int2 p = pack[i];
        float w = __int_as_float(p.y);
        ushort4 u = *(const ushort4*)&X[(size_t)p.x * DIM_D + c4];
        acc[0] += bf2f(u.x) * w; acc[1] += bf2f(u.y) * w;
        acc[2] += bf2f(u.z) * w; acc[3] += bf2f(u.w) * w;
    }
    // combine halves: lane j (<32) += lane j+32
    float t0 = acc[0] + __shfl(acc[0], j + 32);
    float t1 = acc[1] + __shfl(acc[1], j + 32);
    float t2 = acc[2] + __shfl(acc[2], j + 32);
    float t3 = acc[3] + __shfl(acc[3], j + 32);
    if (half == 0)
        *(float4*)&z[(size_t)node * DIM_D + c4] = make_float4(t0, t1, t2, t3);
}

// ---------------- weight transpose+cast: W[K][Nn] fp32 -> Wt[Nn][K] bf16 ----------------
__global__ __launch_bounds__(256) void k_twt(const float* __restrict__ W, u16* __restrict__ Wt,
                                             int K, int Nn) {
    int idx = blockIdx.x * 256 + threadIdx.x;
    if (idx >= K * Nn) return;
    int k = idx / Nn, n = idx - k * Nn;
    Wt[n * K + k] = f2bf(W[idx]);
}

// combined edge-predictor bias: bpq[0..255]=be1, bpq[256..511]=0
__global__ __launch_bounds__(256) void k_bpq(const float* __restrict__ be1, float* __restrict__ bpq) {
    int i = blockIdx.x * 256 + threadIdx.x;
    if (i < 512) bpq[i] = (i < 256) ? be1[i] : 0.f;
}

// ---------------- MFMA GEMM: C[M][Nn] = post(A[M][K] @ W + postB), W given as Wt[Nn][K] bf16 ----
// A_BF16: A is bf16[M][K] else fp32. PRE_BR: A' = relu(A + preB[k]) before cast.
// PERM_PQ: store columns permuted per 64-col group (pq layout for k_edge wide loads).
#define BM 128
#define BN 64
#define BK 32
#define BKP 56   // padded K stride in LDS (bf16 elems)

template <bool A_BF16, bool PRE_BR, bool POST_RELU, bool OUT_BF16, bool PERM_PQ>
__global__ __launch_bounds__(256) void k_gemm(const void* __restrict__ Ap,
                                              const u16* __restrict__ Wt,
                                              const float* __restrict__ preB,
                                              const float* __restrict__ postB,
                                              void* __restrict__ Cp,
                                              int M, int K, int Nn) {
    __shared__ __align__(16) u16 As[BM * BKP];
    __shared__ __align__(16) u16 Bs[BN * BKP];
    const int tid = threadIdx.x;
    const int wid = tid >> 6, lane = tid & 63;
    const int q = lane >> 4, l = lane & 15;
    const int bm = blockIdx.x * BM, bn = blockIdx.y * BN;

    f4 acc[8];
#pragma unroll
    for (int i = 0; i < 8; i++) { f4 zz = {0.f, 0.f, 0.f, 0.f}; acc[i] = zz; }

    for (int k0 = 0; k0 < K; k0 += BK) {
        __syncthreads();
        // stage W tile: Bs[n][k], n in [bn,bn+64), k in [k0,k0+32)
        {
            int n = tid >> 2, kc = (tid & 3) * 8;
            *(int4*)&Bs[n * BKP + kc] = *(const int4*)&Wt[(size_t)(bn + n) * K + k0 + kc];
        }
        // stage A tile: As[m][k]
        if (A_BF16) {
            const u16* A = (const u16*)Ap;
#pragma unroll
            for (int p = 0; p < 2; p++) {
                int m = (tid >> 2) + p * 64, kc = (tid & 3) * 8;
                int gm = bm + m; if (gm >= M) gm = M - 1;
                *(int4*)&As[m * BKP + kc] = *(const int4*)&A[(size_t)gm * K + k0 + kc];
            }
        } else {
            const float* A = (const float*)Ap;
#pragma unroll
            for (int p = 0; p < 4; p++) {
                int m = (tid >> 3) + p * 32, k4 = (tid & 7) * 4;
                int gm = bm + m; if (gm >= M) gm = M - 1;
                float4 v = *(const float4*)&A[(size_t)gm * K + k0 + k4];
                if (PRE_BR) {
                    const float4 pb = *(const float4*)&preB[k0 + k4];
                    v.x = fmaxf(v.x + pb.x, 0.f);
                    v.y = fmaxf(v.y + pb.y, 0.f);
                    v.z = fmaxf(v.z + pb.z, 0.f);
                    v.w = fmaxf(v.w + pb.w, 0.f);
                }
                ushort4 o;
                o.x = f2bf(v.x); o.y = f2bf(v.y); o.z = f2bf(v.z); o.w = f2bf(v.w);
                *(ushort4*)&As[m * BKP + k4] = o;
            }
        }
        __syncthreads();

        s8 af[2], bf[4];
#pragma unroll
        for (int mt = 0; mt < 2; mt++)
            af[mt] = *(const s8*)&As[(wid * 32 + mt * 16 + l) * BKP + q * 8];
#pragma unroll
        for (int nt = 0; nt < 4; nt++)
            bf[nt] = *(const s8*)&Bs[(nt * 16 + l) * BKP + q * 8];
#pragma unroll
        for (int mt = 0; mt < 2; mt++)
#pragma unroll
            for (int nt = 0; nt < 4; nt++)
                acc[mt * 4 + nt] = __builtin_amdgcn_mfma_f32_16x16x32_bf16(
                    af[mt], bf[nt], acc[mt * 4 + nt], 0, 0, 0);
    }

    // epilogue: C row = q*4+r, col = l (per 16x16 tile)
#pragma unroll
    for (int mt = 0; mt < 2; mt++) {
#pragma unroll
        for (int nt = 0; nt < 4; nt++) {
            int colg = bn + nt * 16 + l;                // logical col (bias index)
            float pb = postB ? postB[colg] : 0.0f;
            int cols = colg;
            if (PERM_PQ) {
                int w = colg & 63, mtL = w >> 4;
                cols = (colg & ~63) | (((mtL >> 1) & 1) * 32) | (((w >> 2) & 3) * 8)
                       | ((mtL & 1) * 4) | (w & 3);
            }
#pragma unroll
            for (int r = 0; r < 4; r++) {
                int rowg = bm + wid * 32 + mt * 16 + q * 4 + r;
                if (rowg < M) {
                    float v = acc[mt * 4 + nt][r] + pb;
                    if (POST_RELU) v = fmaxf(v, 0.f);
                    if (OUT_BF16)
                        ((u16*)Cp)[(size_t)rowg * Nn + cols] = f2bf(v);
                    else
                        ((float*)Cp)[(size_t)rowg * Nn + cols] = v;
                }
            }
        }
    }
}

// ---------------- edge predictor: 16 edges (CSR slots) per wave -----------------------------
// v6 (round-4 post-mortem: asm "+v" remat-pin / v_cvt_pk asm caused NaN — both reverted):
//  * weight frags staged in LDS once per block ([mt][l][q] layout => conflict-free ds_read_b64);
//    per-tile re-reads are on the LGKM pipe, removing 32 VMEM loads/tile (round-3 VGPR=84
//    showed the frags were NOT register-resident)
//  * P+Q folded into MFMA-1's C operand (bit-exact: fp32 adds commute)
//  * permuted wide loads + KEEP4 pin + index prefetch (proven in rounds 3)
#if __has_builtin(__builtin_amdgcn_mfma_f32_16x16x16bf16_1k)
#define KEEP4(a,b,c,d) asm volatile("" :: "v"(a), "v"(b), "v"(c), "v"(d))
__global__ __launch_bounds__(256) void k_edge(const u16* __restrict__ PQ,     // [N][512]: P|Q (permuted)
                                              const float* __restrict__ attr,
                                              const int2* __restrict__ pack,
                                              const int2* __restrict__ eidx,
                                              const u16* __restrict__ Wct,    // [256][16] bf16
                                              const u16* __restrict__ We2t,   // [16][256] bf16
                                              const float* __restrict__ be2,
                                              float* __restrict__ outp) {
    // LDS weight tables, fragment-ordered: [mt][l][q] x 4 u16 (8 KB each)
    __shared__ __align__(16) u16 lwc[16 * 64 * 4];
    __shared__ __align__(16) u16 lwe[16 * 64 * 4];
    const int tid = threadIdx.x, wid = tid >> 6, lane = tid & 63;
    const int q = lane >> 4, l = lane & 15;
    for (int u = tid; u < 1024; u += 256) {
        int smt = u >> 6, sl = (u >> 2) & 15, sq = u & 3;
        *(uint2*)&lwc[u * 4] = *(const uint2*)&Wct[(smt * 16 + sl) * 16 + sq * 4];
        *(uint2*)&lwe[u * 4] = *(const uint2*)&We2t[sl * DIM_H + smt * 16 + sq * 4];
    }
    __syncthreads();

    const float4 be2v = *(const float4*)&be2[q * 4];
    const int NT = N_EDGES / 16;
    const int step = gridDim.x * 4;
    const int fbase = (l * 4 + q) * 4;    // lds elem offset of this lane's frag (per mt: +256)

    int tile = blockIdx.x * 4 + wid;
    if (tile >= NT) return;
    int2 pk = pack[tile * 16 + l];        // {src, weight(unused)}
    int2 ec = eidx[tile * 16 + l];        // {orig edge, dst}

    for (; tile < NT; tile += step) {
        const int re = pk.x, e = ec.x, ce = ec.y;
        const u16* prow = PQ + (size_t)re * 512 + q * 8;          // P half (random, LLC)
        const u16* qrow = PQ + (size_t)ce * 512 + 256 + q * 8;    // Q half (CSR runs, L1)

        // issue the whole gather batch: attr + 16 wide P/Q loads (16B/lane, 64B/edge/instr)
        float4 av = *(const float4*)&attr[(size_t)e * DIM_A + q * 4];
        s8 pw[8], qw[8];
#pragma unroll
        for (int w = 0; w < 8; w++) {
            pw[w] = *(const s8*)(prow + w * 32);
            qw[w] = *(const s8*)(qrow + w * 32);
        }
        // prefetch next tile's indices (independent of current compute)
        int ntile = tile + step;
        int ns = (ntile < NT) ? ntile * 16 + l : l;
        int2 pk_n = pack[ns];
        int2 ec_n = eidx[ns];
        // pin: force all batch results live here (IR sinking cannot cross asm operands)
        KEEP4(pw[0], pw[1], pw[2], pw[3]);
        KEEP4(pw[4], pw[5], pw[6], pw[7]);
        KEEP4(qw[0], qw[1], qw[2], qw[3]);
        KEEP4(qw[4], qw[5], qw[6], qw[7]);
        __builtin_amdgcn_sched_barrier(0);

        s4 af;   // attr B-frag: B[k=q*4+j][n=edge=l]
        af[0] = (short)f2bf(av.x); af[1] = (short)f2bf(av.y);
        af[2] = (short)f2bf(av.z); af[3] = (short)f2bf(av.w);

        f4 acc2 = {0.f, 0.f, 0.f, 0.f};
#pragma unroll
        for (int w = 0; w < 8; w++) {
#pragma unroll
            for (int s = 0; s < 2; s++) {
                const int mt = w * 2 + s;
                s4 wcf = *(const s4*)&lwc[mt * 256 + fbase];
                // C-in = P+Q (layout: reg j <-> row q*4+j, col l — matches D exactly)
                f4 pqs;
                pqs[0] = bf2f((u16)pw[w][s * 4 + 0]) + bf2f((u16)qw[w][s * 4 + 0]);
                pqs[1] = bf2f((u16)pw[w][s * 4 + 1]) + bf2f((u16)qw[w][s * 4 + 1]);
                pqs[2] = bf2f((u16)pw[w][s * 4 + 2]) + bf2f((u16)qw[w][s * 4 + 2]);
                pqs[3] = bf2f((u16)pw[w][s * 4 + 3]) + bf2f((u16)qw[w][s * 4 + 3]);
                f4 acc = __builtin_amdgcn_mfma_f32_16x16x16bf16_1k(wcf, af, pqs, 0, 0, 0);
                s4 uf;   // B-frag of u^T: lane (q,l) -> edge l, k = mt*16 + q*4 + j
                uf[0] = (short)f2bf(fmaxf(acc[0], 0.f));
                uf[1] = (short)f2bf(fmaxf(acc[1], 0.f));
                uf[2] = (short)f2bf(fmaxf(acc[2], 0.f));
                uf[3] = (short)f2bf(fmaxf(acc[3], 0.f));
                s4 wef = *(const s4*)&lwe[mt * 256 + fbase];
                acc2 = __builtin_amdgcn_mfma_f32_16x16x16bf16_1k(wef, uf, acc2, 0, 0, 0);
            }
        }
        // D: col=edge l, row=outcol q*4+r -> one 64B store per edge row (scatter via e)
        *(float4*)&outp[(size_t)e * DIM_A + q * 4] =
            make_float4(acc2[0] + be2v.x, acc2[1] + be2v.y,
                        acc2[2] + be2v.z, acc2[3] + be2v.w);
        pk = pk_n; ec = ec_n;
    }
}
#else
// Fallback (x32 MFMA + per-wave LDS round-trip), operand-swapped MFMA-2 + float4 store.
// NOTE: consumes the SAME permuted PQ layout via pq_off(mt,q).
#define UPAD 268   // row stride 134 dwords (≡6 mod 32) — breaks the q-stride/l-stride alignment
__global__ __launch_bounds__(256) void k_edge(const u16* __restrict__ PQ,
                                              const float* __restrict__ attr,
                                              const int2* __restrict__ pack,
                                              const int2* __restrict__ eidx,
                                              const u16* __restrict__ Wct,
                                              const u16* __restrict__ We2t,
                                              const float* __restrict__ be2,
                                              float* __restrict__ outp) {
    __shared__ __align__(16) u16 ub[4][16][UPAD];
    const int tid = threadIdx.x, wid = tid >> 6, lane = tid & 63;
    const int q = lane >> 4, l = lane & 15;
    const float4 be2v = *(const float4*)&be2[q * 4];
    u16(*u)[UPAD] = ub[wid];

    s8 wcf[16];
#pragma unroll
    for (int mt = 0; mt < 16; mt++) {
        wcf[mt] = zero_s8();
        if (q < 2) wcf[mt] = *(const s8*)&Wct[(mt * 16 + l) * 16 + q * 8];
    }

    for (int tile = blockIdx.x * 4 + wid; tile < N_EDGES / 16; tile += gridDim.x * 4) {
        const int s = tile * 16 + l;
        const int2 pk = pack[s];
        const int2 ec = eidx[s];
        const int re = pk.x, e = ec.x, ce = ec.y;
        const u16* prow = PQ + (size_t)re * 512;
        const u16* qrow = PQ + (size_t)ce * 512 + 256;

        s8 af = zero_s8();
        if (q < 2) {
            const float* ap = &attr[(size_t)e * DIM_A + q * 8];
            float4 a0 = *(const float4*)ap;
            float4 a1 = *(const float4*)(ap + 4);
            af[0] = (short)f2bf(a0.x); af[1] = (short)f2bf(a0.y);
            af[2] = (short)f2bf(a0.z); af[3] = (short)f2bf(a0.w);
            af[4] = (short)f2bf(a1.x); af[5] = (short)f2bf(a1.y);
            af[6] = (short)f2bf(a1.z); af[7] = (short)f2bf(a1.w);
        }

#pragma unroll
        for (int mt = 0; mt < 16; mt++) {
            f4 cz = {0.f, 0.f, 0.f, 0.f};
            f4 acc = __builtin_amdgcn_mfma_f32_16x16x32_bf16(wcf[mt], af, cz, 0, 0, 0);
            ushort4 pu = *(const ushort4*)(prow + pq_off(mt, q));
            ushort4 qu = *(const ushort4*)(qrow + pq_off(mt, q));
            float t0 = bf2f(pu.x) + bf2f(qu.x) + acc[0];
            float t1 = bf2f(pu.y) + bf2f(qu.y) + acc[1];
            float t2 = bf2f(pu.z) + bf2f(qu.z) + acc[2];
            float t3 = bf2f(pu.w) + bf2f(qu.w) + acc[3];
            ushort4 o;
            o.x = f2bf(fmaxf(t0, 0.f)); o.y = f2bf(fmaxf(t1, 0.f));
            o.z = f2bf(fmaxf(t2, 0.f)); o.w = f2bf(fmaxf(t3, 0.f));
            *(ushort4*)&u[l][mt * 16 + q * 4] = o;
        }

        f4 acc2 = {0.f, 0.f, 0.f, 0.f};
#pragma unroll
        for (int ks = 0; ks < 8; ks++) {
            s8 uf = *(const s8*)&u[l][ks * 32 + q * 8];
            s8 wf = *(const s8*)&We2t[(size_t)l * DIM_H + ks * 32 + q * 8];
            acc2 = __builtin_amdgcn_mfma_f32_16x16x32_bf16(wf, uf, acc2, 0, 0, 0);
        }
        *(float4*)&outp[(size_t)e * DIM_A + q * 4] =
            make_float4(acc2[0] + be2v.x, acc2[1] + be2v.y,
                        acc2[2] + be2v.z, acc2[3] + be2v.w);
    }
}
#endif

extern "C" void kernel_launch(void* const* d_in, const int* in_sizes, int n_in,
                              void* d_out, int out_size, void* d_ws, size_t ws_size,
                              hipStream_t stream) {
    (void)in_sizes; (void)n_in; (void)out_size; (void)ws_size;
    const float* x    = (const float*)d_in[0];
    const int*   ei   = (const int*)d_in[1];
    const float* attr = (const float*)d_in[2];
    const float* W1   = (const float*)d_in[3];
    const float* b1   = (const float*)d_in[4];
    const float* W2   = (const float*)d_in[5];
    const float* b2   = (const float*)d_in[6];
    const float* Wo1  = (const float*)d_in[7];
    const float* bo1  = (const float*)d_in[8];
    const float* Wo2  = (const float*)d_in[9];
    const float* bo2  = (const float*)d_in[10];
    const float* We1  = (const float*)d_in[11];
    const float* be1  = (const float*)d_in[12];
    const float* We2  = (const float*)d_in[13];
    const float* be2  = (const float*)d_in[14];
    const int* rowi = ei;
    const int* coli = ei + N_EDGES;

    float* hout = (float*)d_out;                       // [N][128]
    float* eout = hout + (size_t)N_NODES * DIM_D;      // [E][16]

    char* ws = (char*)d_ws;
    size_t off = 0;
    auto nxt = [&](size_t b) -> void* {
        void* p = ws + off; off = (off + b + 255) & ~(size_t)255; return p;
    };
    float* dinv = (float*)nxt((size_t)N_NODES * 4);
    int* cnt    = (int*)nxt((size_t)N_NODES * 4);
    int* startp = (int*)nxt((size_t)(N_NODES + 1) * 4);
    int* cursor = (int*)nxt((size_t)N_NODES * 4);
    int2* pack  = (int2*)nxt((size_t)N_EDGES * 8);
    int2* eidx  = (int2*)nxt((size_t)N_EDGES * 8);
    u16* W1t   = (u16*)nxt(128 * 256 * 2);
    u16* W2t   = (u16*)nxt(128 * 256 * 2);
    u16* Wo1t  = (u16*)nxt(128 * 256 * 2);
    u16* Wo2t  = (u16*)nxt(128 * 256 * 2);
    u16* Wabt  = (u16*)nxt(512 * 128 * 2);   // [512][128]: Wa^T | Wb^T
    u16* Wct   = (u16*)nxt(256 * 16 * 2);
    u16* We2t  = (u16*)nxt(16 * 256 * 2);
    float* bpq = (float*)nxt(512 * 4);
    u16* xb    = (u16*)nxt((size_t)N_NODES * DIM_D * 2);     // x cast to bf16
    float* z   = (float*)nxt((size_t)N_NODES * DIM_D * 4);   // Âx / Ây accumulator (fp32)
    u16* h1    = (u16*)nxt((size_t)N_NODES * DIM_H * 2);     // intermediate [N][256]
    u16* yb    = (u16*)nxt((size_t)N_NODES * DIM_D * 2);
    // PQ [N][512] bf16 (51.2 MB) overlays z+h1 (both dead once hout is computed)
    u16* PQb = (u16*)z;

    const int gN = (N_NODES + 255) / 256;
    const int gE = (N_EDGES + 255) / 256;

    // weight transposes (bf16)
    k_twt<<<(128 * 256 + 255) / 256, 256, 0, stream>>>(W1, W1t, 128, 256);
    k_twt<<<(128 * 256 + 255) / 256, 256, 0, stream>>>(W2, W2t, 256, 128);
    k_twt<<<(128 * 256 + 255) / 256, 256, 0, stream>>>(Wo1, Wo1t, 128, 256);
    k_twt<<<(128 * 256 + 255) / 256, 256, 0, stream>>>(Wo2, Wo2t, 256, 128);
    k_twt<<<(128 * 256 + 255) / 256, 256, 0, stream>>>(We1, Wabt, 128, 256);
    k_twt<<<(128 * 256 + 255) / 256, 256, 0, stream>>>(We1 + 128 * 256, Wabt + 256 * 128, 128, 256);
    k_twt<<<(16 * 256 + 255) / 256, 256, 0, stream>>>(We1 + 256 * 256, Wct, 16, 256);
    k_twt<<<(16 * 256 + 255) / 256, 256, 0, stream>>>(We2, We2t, 256, 16);
    k_bpq<<<2, 256, 0, stream>>>(be1, bpq);

    // ---- CSR build (once; reused by both gather layers + edge predictor order) ----
    k_zero<<<gN, 256, 0, stream>>>(cnt);
    k_count<<<gE, 256, 0, stream>>>(coli, cnt);
    k_dinv<<<gN, 256, 0, stream>>>(cnt, dinv);
    k_scan<<<1, 1024, 0, stream>>>(cnt, startp);
    k_copy<<<gN, 256, 0, stream>>>(startp, cursor);
    k_fill<<<gE, 256, 0, stream>>>(rowi, coli, dinv, cursor, pack, eidx);

    // cast x -> bf16 (halves layer-1 gather traffic)
    k_cast<<<(N_NODES * DIM_D / 4 + 255) / 256, 256, 0, stream>>>(x, xb, N_NODES * DIM_D / 4);

    dim3 g4(391, 4), g2(391, 2), g8(391, 8);
    const int gG = (N_NODES + 3) / 4;   // 4 nodes (waves) per block
    // layer 1: z = Âx ; h1 = relu(z@W1 + b1)
    k_gather<<<gG, 256, 0, stream>>>(xb, pack, startp, dinv, z);
    k_gemm<false, false, true, true, false><<<g4, 256, 0, stream>>>(z, W1t, nullptr, b1, h1, N_NODES, 128, 256);
    // layer 2: y = h1@W2 ; z = Ây ; h2 = relu(z + b2) fused into next GEMM's A-stage
    k_gemm<true, false, false, true, false><<<g2, 256, 0, stream>>>(h1, W2t, nullptr, nullptr, yb, N_NODES, 256, 128);
    k_gather<<<gG, 256, 0, stream>>>(yb, pack, startp, dinv, z);
    // output MLP: h3 = relu(relu(z+b2)@Wo1 + bo1) ; h = h3@Wo2 + bo2 -> d_out (fp32)
    k_gemm<false, true, true, true, false><<<g4, 256, 0, stream>>>(z, Wo1t, b2, bo1, h1, N_NODES, 128, 256);
    k_gemm<true, false, false, false, false><<<g2, 256, 0, stream>>>(h1, Wo2t, nullptr, bo2, hout, N_NODES, 256, 128);
    // edge predictor precompute (single fused GEMM): PQ = [h@Wa + be1 | h@Wb]  (bf16, [N][512], permuted cols)
    k_gemm<false, false, false, true, true><<<g8, 256, 0, stream>>>(hout, Wabt, nullptr, bpq, PQb, N_NODES, 128, 512);
    // per-edge (CSR slot order): out = relu(P[src]+Q[dst]+attr@Wc)@We2 + be2
    k_edge<<<2048, 256, 0, stream>>>(PQb, attr, pack, eidx, Wct, We2t, be2, eout);
}

// Round 6
// 654.281 us; speedup vs baseline: 1.1132x; 1.0196x over previous
//
#include <hip/hip_runtime.h>
#include <hip/hip_bf16.h>

// Problem constants (from reference): N=50000, E=800000, D=128, H=256, A=16
#define N_NODES 50000
#define N_EDGES 800000
#define DIM_D   128
#define DIM_H   256
#define DIM_A   16

typedef unsigned short u16;
typedef __attribute__((ext_vector_type(4))) float f4;
typedef __attribute__((ext_vector_type(8))) short s8;
typedef __attribute__((ext_vector_type(4))) short s4;

__device__ __forceinline__ u16 f2bf(float f) {
    union { float f; unsigned u; } v; v.f = f;
    unsigned r = v.u + 0x7FFFu + ((v.u >> 16) & 1u);   // RNE
    return (u16)(r >> 16);
}
__device__ __forceinline__ float bf2f(u16 s) {
    union { unsigned u; float f; } v; v.u = ((unsigned)s) << 16; return v.f;
}
__device__ __forceinline__ s8 zero_s8() {
    s8 v;
#pragma unroll
    for (int i = 0; i < 8; i++) v[i] = 0;
    return v;
}
// HW-packed f32->bf16 via HIP intrinsics (compiler emits v_cvt_pk_bf16_f32; RNE, no inline asm)
__device__ __forceinline__ s4 pk_bf16x4(float a, float b, float c, float d) {
    __hip_bfloat162 h0 = __float22bfloat162_rn(make_float2(a, b));
    __hip_bfloat162 h1 = __float22bfloat162_rn(make_float2(c, d));
    s4 v;
    __builtin_memcpy(&v, &h0, 4);
    __builtin_memcpy(((char*)&v) + 4, &h1, 4);
    return v;
}
__device__ __forceinline__ u16 f2bf_hw(float f) {
    __hip_bfloat16 h = __float2bfloat16(f);
    u16 u; __builtin_memcpy(&u, &h, 2);
    return u;
}

// ---- PQ permuted column layout (within each 64-col group of a PQ row) ----
// stored[i*32 + q*8 + s*4 + j] = logical[(2i+s)*16 + q*4 + j]
// => lane q reads ONE dwordx4 (16B) per (group,i) covering its chunks for mt'=2i and 2i+1.
__device__ __forceinline__ int pq_off(int mt, int q) {   // stored elem offset of logical chunk (mt, q)
    return (mt >> 2) * 64 + ((mt >> 1) & 1) * 32 + q * 8 + (mt & 1) * 4;
}

// ---------------- CSR build ----------------
__global__ __launch_bounds__(256) void k_zero(int* __restrict__ cnt) {
    int i = blockIdx.x * 256 + threadIdx.x;
    if (i < N_NODES) cnt[i] = 0;
}
__global__ __launch_bounds__(256) void k_count(const int* __restrict__ coli, int* __restrict__ cnt) {
    int e = blockIdx.x * 256 + threadIdx.x;
    if (e < N_EDGES) atomicAdd(&cnt[coli[e]], 1);
}
__global__ __launch_bounds__(256) void k_dinv(const int* __restrict__ cnt, float* __restrict__ dinv) {
    int i = blockIdx.x * 256 + threadIdx.x;
    if (i < N_NODES) dinv[i] = rsqrtf((float)(cnt[i] + 1));   // +1 self-loop
}

#define SCAN_C 49   // 1024 * 49 = 50176 >= N_NODES
__global__ __launch_bounds__(1024) void k_scan(const int* __restrict__ cnt, int* __restrict__ start) {
    __shared__ int ps[1024];
    int t = threadIdx.x;
    int base = t * SCAN_C;
    int sum = 0;
    for (int i = 0; i < SCAN_C; i++) {
        int idx = base + i;
        sum += (idx < N_NODES) ? cnt[idx] : 0;
    }
    ps[t] = sum;
    __syncthreads();
    for (int ofs = 1; ofs < 1024; ofs <<= 1) {
        int v = (t >= ofs) ? ps[t - ofs] : 0;
        __syncthreads();
        ps[t] += v;
        __syncthreads();
    }
    int run = (t > 0) ? ps[t - 1] : 0;
    for (int i = 0; i < SCAN_C; i++) {
        int idx = base + i;
        if (idx < N_NODES) {
            start[idx] = run;
            run += cnt[idx];
        }
    }
    if (t == 1023) start[N_NODES] = ps[1023];
}
__global__ __launch_bounds__(256) void k_copy(const int* __restrict__ start, int* __restrict__ cursor) {
    int i = blockIdx.x * 256 + threadIdx.x;
    if (i < N_NODES) cursor[i] = start[i];
}
// pack[slot] = {src_node, dinv[src]*dinv[dst]} bucketed by destination
// eidx[slot] = {orig_edge, dst_node} (for CSR-ordered edge predictor)
__global__ __launch_bounds__(256) void k_fill(const int* __restrict__ rowi, const int* __restrict__ coli,
                                              const float* __restrict__ dinv,
                                              int* __restrict__ cursor, int2* __restrict__ pack,
                                              int2* __restrict__ eidx) {
    int e = blockIdx.x * 256 + threadIdx.x;
    if (e >= N_EDGES) return;
    int r = rowi[e], c = coli[e];
    int slot = atomicAdd(&cursor[c], 1);
    float w = dinv[r] * dinv[c];
    pack[slot] = make_int2(r, __float_as_int(w));
    eidx[slot] = make_int2(e, c);
}

// ---------------- fp32 -> bf16 cast (x table) ----------------
__global__ __launch_bounds__(256) void k_cast(const float* __restrict__ X, u16* __restrict__ Y, int n4) {
    int i = blockIdx.x * 256 + threadIdx.x;
    if (i >= n4) return;
    float4 v = *(const float4*)&X[(size_t)i * 4];
    ushort4 o;
    o.x = f2bf(v.x); o.y = f2bf(v.y); o.z = f2bf(v.z); o.w = f2bf(v.w);
    *(ushort4*)&Y[(size_t)i * 4] = o;
}

// ---------------- CSR gather: z[n] = X[n]*dinv[n]^2 + sum_{e->n} X[src]*w ----------------
// one wave per node; two 32-lane halves take contiguous sub-ranges of the CSR span
// (contiguous => 4-deep independent load batches), lane covers 4 cols (bf16 X)
__global__ __launch_bounds__(256) void k_gather(const u16* __restrict__ X,
                                                const int2* __restrict__ pack,
                                                const int* __restrict__ start,
                                                const float* __restrict__ dinv,
                                                float* __restrict__ z) {
    int node = blockIdx.x * 4 + (threadIdx.x >> 6);
    if (node >= N_NODES) return;
    int lane = threadIdx.x & 63;
    int half = lane >> 5, j = lane & 31;
    int c4 = j * 4;
    float di = dinv[node];
    f4 acc = {0.f, 0.f, 0.f, 0.f};
    if (half == 0) {
        float sl = di * di;
        ushort4 u = *(const ushort4*)&X[(size_t)node * DIM_D + c4];
        acc[0] = bf2f(u.x) * sl; acc[1] = bf2f(u.y) * sl;
        acc[2] = bf2f(u.z) * sl; acc[3] = bf2f(u.w) * sl;
    }
    int s0 = start[node], e0 = start[node + 1];
    int h0 = (e0 - s0 + 1) >> 1;
    int i   = half ? (s0 + h0) : s0;
    int end = half ? e0 : (s0 + h0);
    // 4-deep software pipeline: 4 independent pack loads, then 4 row loads in flight
    for (; i + 3 < end; i += 4) {
        int2 p0 = pack[i], p1 = pack[i + 1], p2 = pack[i + 2], p3 = pack[i + 3];
        ushort4 u0 = *(const ushort4*)&X[(size_t)p0.x * DIM_D + c4];
        ushort4 u1 = *(const ushort4*)&X[(size_t)p1.x * DIM_D + c4];
        ushort4 u2 = *(const ushort4*)&X[(size_t)p2.x * DIM_D + c4];
        ushort4 u3 = *(const ushort4*)&X[(size_t)p3.x * DIM_D + c4];
        float w0 = __int_as_float(p0.y), w1 = __int_as_float(p1.y);
        float w2 = __int_as_float(p2.y), w3 = __int_as_float(p3.y);
        acc[0] += bf2f(u0.x) * w0; acc[1] += bf2f(u0.y) * w0;
        acc[2] += bf2f(u0.z) * w0; acc[3] += bf2f(u0.w) * w0;
        acc[0] += bf2f(u1.x) * w1; acc[1] += bf2f(u1.y) * w1;
        acc[2] += bf2f(u1.z) * w1; acc[3] += bf2f(u1.w) * w1;
        acc[0] += bf2f(u2.x) * w2; acc[1] += bf2f(u2.y) * w2;
        acc[2] += bf2f(u2.z) * w2; acc[3] += bf2f(u2.w) * w2;
        acc[0] += bf2f(u3.x) * w3; acc[1] += bf2f(u3.y) * w3;
        acc[2] += bf2f(u3.z) * w3; acc[3] += bf2f(u3.w) * w3;
    }
    for (; i < end; i++) {
        int2 p = pack[i];
        float w = __int_as_float(p.y);
        ushort4 u = *(const ushort4*)&X[(size_t)p.x * DIM_D + c4];
        acc[0] += bf2f(u.x) * w; acc[1] += bf2f(u.y) * w;
        acc[2] += bf2f(u.z) * w; acc[3] += bf2f(u.w) * w;
    }
    // combine halves: lane j (<32) += lane j+32
    float t0 = acc[0] + __shfl(acc[0], j + 32);
    float t1 = acc[1] + __shfl(acc[1], j + 32);
    float t2 = acc[2] + __shfl(acc[2], j + 32);
    float t3 = acc[3] + __shfl(acc[3], j + 32);
    if (half == 0)
        *(float4*)&z[(size_t)node * DIM_D + c4] = make_float4(t0, t1, t2, t3);
}

// ---------------- weight transpose+cast: W[K][Nn] fp32 -> Wt[Nn][K] bf16 ----------------
__global__ __launch_bounds__(256) void k_twt(const float* __restrict__ W, u16* __restrict__ Wt,
                                             int K, int Nn) {
    int idx = blockIdx.x * 256 + threadIdx.x;
    if (idx >= K * Nn) return;
    int k = idx / Nn, n = idx - k * Nn;
    Wt[n * K + k] = f2bf(W[idx]);
}

// combined edge-predictor bias: bpq[0..255]=be1, bpq[256..511]=0
__global__ __launch_bounds__(256) void k_bpq(const float* __restrict__ be1, float* __restrict__ bpq) {
    int i = blockIdx.x * 256 + threadIdx.x;
    if (i < 512) bpq[i] = (i < 256) ? be1[i] : 0.f;
}

// ---------------- MFMA GEMM: C[M][Nn] = post(A[M][K] @ W + postB), W given as Wt[Nn][K] bf16 ----
// A_BF16: A is bf16[M][K] else fp32. PRE_BR: A' = relu(A + preB[k]) before cast.
// PERM_PQ: store columns permuted per 64-col group (pq layout for k_edge wide loads).
#define BM 128
#define BN 64
#define BK 32
#define BKP 56   // padded K stride in LDS (bf16 elems)

template <bool A_BF16, bool PRE_BR, bool POST_RELU, bool OUT_BF16, bool PERM_PQ>
__global__ __launch_bounds__(256) void k_gemm(const void* __restrict__ Ap,
                                              const u16* __restrict__ Wt,
                                              const float* __restrict__ preB,
                                              const float* __restrict__ postB,
                                              void* __restrict__ Cp,
                                              int M, int K, int Nn) {
    __shared__ __align__(16) u16 As[BM * BKP];
    __shared__ __align__(16) u16 Bs[BN * BKP];
    const int tid = threadIdx.x;
    const int wid = tid >> 6, lane = tid & 63;
    const int q = lane >> 4, l = lane & 15;
    const int bm = blockIdx.x * BM, bn = blockIdx.y * BN;

    f4 acc[8];
#pragma unroll
    for (int i = 0; i < 8; i++) { f4 zz = {0.f, 0.f, 0.f, 0.f}; acc[i] = zz; }

    for (int k0 = 0; k0 < K; k0 += BK) {
        __syncthreads();
        // stage W tile: Bs[n][k], n in [bn,bn+64), k in [k0,k0+32)
        {
            int n = tid >> 2, kc = (tid & 3) * 8;
            *(int4*)&Bs[n * BKP + kc] = *(const int4*)&Wt[(size_t)(bn + n) * K + k0 + kc];
        }
        // stage A tile: As[m][k]
        if (A_BF16) {
            const u16* A = (const u16*)Ap;
#pragma unroll
            for (int p = 0; p < 2; p++) {
                int m = (tid >> 2) + p * 64, kc = (tid & 3) * 8;
                int gm = bm + m; if (gm >= M) gm = M - 1;
                *(int4*)&As[m * BKP + kc] = *(const int4*)&A[(size_t)gm * K + k0 + kc];
            }
        } else {
            const float* A = (const float*)Ap;
#pragma unroll
            for (int p = 0; p < 4; p++) {
                int m = (tid >> 3) + p * 32, k4 = (tid & 7) * 4;
                int gm = bm + m; if (gm >= M) gm = M - 1;
                float4 v = *(const float4*)&A[(size_t)gm * K + k0 + k4];
                if (PRE_BR) {
                    const float4 pb = *(const float4*)&preB[k0 + k4];
                    v.x = fmaxf(v.x + pb.x, 0.f);
                    v.y = fmaxf(v.y + pb.y, 0.f);
                    v.z = fmaxf(v.z + pb.z, 0.f);
                    v.w = fmaxf(v.w + pb.w, 0.f);
                }
                s4 o = pk_bf16x4(v.x, v.y, v.z, v.w);
                *(s4*)&As[m * BKP + k4] = o;
            }
        }
        __syncthreads();

        s8 af[2], bf[4];
#pragma unroll
        for (int mt = 0; mt < 2; mt++)
            af[mt] = *(const s8*)&As[(wid * 32 + mt * 16 + l) * BKP + q * 8];
#pragma unroll
        for (int nt = 0; nt < 4; nt++)
            bf[nt] = *(const s8*)&Bs[(nt * 16 + l) * BKP + q * 8];
#pragma unroll
        for (int mt = 0; mt < 2; mt++)
#pragma unroll
            for (int nt = 0; nt < 4; nt++)
                acc[mt * 4 + nt] = __builtin_amdgcn_mfma_f32_16x16x32_bf16(
                    af[mt], bf[nt], acc[mt * 4 + nt], 0, 0, 0);
    }

    // epilogue: C row = q*4+r, col = l (per 16x16 tile)
#pragma unroll
    for (int mt = 0; mt < 2; mt++) {
#pragma unroll
        for (int nt = 0; nt < 4; nt++) {
            int colg = bn + nt * 16 + l;                // logical col (bias index)
            float pb = postB ? postB[colg] : 0.0f;
            int cols = colg;
            if (PERM_PQ) {
                int w = colg & 63, mtL = w >> 4;
                cols = (colg & ~63) | (((mtL >> 1) & 1) * 32) | (((w >> 2) & 3) * 8)
                       | ((mtL & 1) * 4) | (w & 3);
            }
#pragma unroll
            for (int r = 0; r < 4; r++) {
                int rowg = bm + wid * 32 + mt * 16 + q * 4 + r;
                if (rowg < M) {
                    float v = acc[mt * 4 + nt][r] + pb;
                    if (POST_RELU) v = fmaxf(v, 0.f);
                    if (OUT_BF16)
                        ((u16*)Cp)[(size_t)rowg * Nn + cols] = f2bf_hw(v);
                    else
                        ((float*)Cp)[(size_t)rowg * Nn + cols] = v;
                }
            }
        }
    }
}

// ---------------- edge predictor: 16 edges (CSR slots) per wave -----------------------------
// v7 (on v6): round-5 PMC showed SQ_LDS_BANK_CONFLICT=1.92e7 — the [mt][l][q] frag table hit
// only 8 even banks per 32-lane phase (4-way conflict on every ds_read_b64). Fixes:
//  * lane-major interleaved table lw[mt][q*16+l][wc0..3|we0..3]: lane i reads byte i*16 —
//    conflict-free, and ONE ds_read_b128 yields both frags (32 -> 16 LDS instrs/tile)
//  * all f32->bf16 via __float22bfloat162_rn (compiler emits v_cvt_pk_bf16_f32; RNE; no asm)
#if __has_builtin(__builtin_amdgcn_mfma_f32_16x16x16bf16_1k)
#define KEEP4(a,b,c,d) asm volatile("" :: "v"(a), "v"(b), "v"(c), "v"(d))
__global__ __launch_bounds__(256) void k_edge(const u16* __restrict__ PQ,     // [N][512]: P|Q (permuted)
                                              const float* __restrict__ attr,
                                              const int2* __restrict__ pack,
                                              const int2* __restrict__ eidx,
                                              const u16* __restrict__ Wct,    // [256][16] bf16
                                              const u16* __restrict__ We2t,   // [16][256] bf16
                                              const float* __restrict__ be2,
                                              float* __restrict__ outp) {
    // interleaved weight table: [mt][lane=q*16+l] x {wc frag (4 u16), we frag (4 u16)} = 16 KB
    __shared__ __align__(16) u16 lw[16 * 64 * 8];
    const int tid = threadIdx.x, wid = tid >> 6, lane = tid & 63;
    const int q = lane >> 4, l = lane & 15;
    for (int u = tid; u < 1024; u += 256) {
        int smt = u >> 6, sq = (u >> 4) & 3, sl = u & 15;
        *(uint2*)&lw[u * 8]     = *(const uint2*)&Wct[(smt * 16 + sl) * 16 + sq * 4];
        *(uint2*)&lw[u * 8 + 4] = *(const uint2*)&We2t[sl * DIM_H + smt * 16 + sq * 4];
    }
    __syncthreads();

    const float4 be2v = *(const float4*)&be2[q * 4];
    const int NT = N_EDGES / 16;
    const int step = gridDim.x * 4;
    const int lbase = lane * 8;           // lds elem offset of this lane's frag pair (per mt: +512)

    int tile = blockIdx.x * 4 + wid;
    if (tile >= NT) return;
    int2 pk = pack[tile * 16 + l];        // {src, weight(unused)}
    int2 ec = eidx[tile * 16 + l];        // {orig edge, dst}

    for (; tile < NT; tile += step) {
        const int re = pk.x, e = ec.x, ce = ec.y;
        const u16* prow = PQ + (size_t)re * 512 + q * 8;          // P half (random, LLC)
        const u16* qrow = PQ + (size_t)ce * 512 + 256 + q * 8;    // Q half (CSR runs, L1)

        // issue the whole gather batch: attr + 16 wide P/Q loads (16B/lane, 64B/edge/instr)
        float4 av = *(const float4*)&attr[(size_t)e * DIM_A + q * 4];
        s8 pw[8], qw[8];
#pragma unroll
        for (int w = 0; w < 8; w++) {
            pw[w] = *(const s8*)(prow + w * 32);
            qw[w] = *(const s8*)(qrow + w * 32);
        }
        // prefetch next tile's indices (independent of current compute)
        int ntile = tile + step;
        int ns = (ntile < NT) ? ntile * 16 + l : l;
        int2 pk_n = pack[ns];
        int2 ec_n = eidx[ns];
        // pin: force all batch results live here (IR sinking cannot cross asm operands)
        KEEP4(pw[0], pw[1], pw[2], pw[3]);
        KEEP4(pw[4], pw[5], pw[6], pw[7]);
        KEEP4(qw[0], qw[1], qw[2], qw[3]);
        KEEP4(qw[4], qw[5], qw[6], qw[7]);
        __builtin_amdgcn_sched_barrier(0);

        s4 af = pk_bf16x4(av.x, av.y, av.z, av.w);   // attr B-frag: B[k=q*4+j][n=edge=l]

        f4 acc2 = {0.f, 0.f, 0.f, 0.f};
#pragma unroll
        for (int w = 0; w < 8; w++) {
#pragma unroll
            for (int s = 0; s < 2; s++) {
                const int mt = w * 2 + s;
                s8 wf = *(const s8*)&lw[mt * 512 + lbase];
                s4 wcf = {wf[0], wf[1], wf[2], wf[3]};
                s4 wef = {wf[4], wf[5], wf[6], wf[7]};
                // C-in = P+Q (layout: reg j <-> row q*4+j, col l — matches D exactly)
                f4 pqs;
                pqs[0] = bf2f((u16)pw[w][s * 4 + 0]) + bf2f((u16)qw[w][s * 4 + 0]);
                pqs[1] = bf2f((u16)pw[w][s * 4 + 1]) + bf2f((u16)qw[w][s * 4 + 1]);
                pqs[2] = bf2f((u16)pw[w][s * 4 + 2]) + bf2f((u16)qw[w][s * 4 + 2]);
                pqs[3] = bf2f((u16)pw[w][s * 4 + 3]) + bf2f((u16)qw[w][s * 4 + 3]);
                f4 acc = __builtin_amdgcn_mfma_f32_16x16x16bf16_1k(wcf, af, pqs, 0, 0, 0);
                s4 uf = pk_bf16x4(fmaxf(acc[0], 0.f), fmaxf(acc[1], 0.f),
                                  fmaxf(acc[2], 0.f), fmaxf(acc[3], 0.f));
                acc2 = __builtin_amdgcn_mfma_f32_16x16x16bf16_1k(wef, uf, acc2, 0, 0, 0);
            }
        }
        // D: col=edge l, row=outcol q*4+r -> one 64B store per edge row (scatter via e)
        *(float4*)&outp[(size_t)e * DIM_A + q * 4] =
            make_float4(acc2[0] + be2v.x, acc2[1] + be2v.y,
                        acc2[2] + be2v.z, acc2[3] + be2v.w);
        pk = pk_n; ec = ec_n;
    }
}
#else
// Fallback (x32 MFMA + per-wave LDS round-trip), operand-swapped MFMA-2 + float4 store.
// NOTE: consumes the SAME permuted PQ layout via pq_off(mt,q).
#define UPAD 268   // row stride 134 dwords (≡6 mod 32) — breaks the q-stride/l-stride alignment
__global__ __launch_bounds__(256) void k_edge(const u16* __restrict__ PQ,
                                              const float* __restrict__ attr,
                                              const int2* __restrict__ pack,
                                              const int2* __restrict__ eidx,
                                              const u16* __restrict__ Wct,
                                              const u16* __restrict__ We2t,
                                              const float* __restrict__ be2,
                                              float* __restrict__ outp) {
    __shared__ __align__(16) u16 ub[4][16][UPAD];
    const int tid = threadIdx.x, wid = tid >> 6, lane = tid & 63;
    const int q = lane >> 4, l = lane & 15;
    const float4 be2v = *(const float4*)&be2[q * 4];
    u16(*u)[UPAD] = ub[wid];

    s8 wcf[16];
#pragma unroll
    for (int mt = 0; mt < 16; mt++) {
        wcf[mt] = zero_s8();
        if (q < 2) wcf[mt] = *(const s8*)&Wct[(mt * 16 + l) * 16 + q * 8];
    }

    for (int tile = blockIdx.x * 4 + wid; tile < N_EDGES / 16; tile += gridDim.x * 4) {
        const int s = tile * 16 + l;
        const int2 pk = pack[s];
        const int2 ec = eidx[s];
        const int re = pk.x, e = ec.x, ce = ec.y;
        const u16* prow = PQ + (size_t)re * 512;
        const u16* qrow = PQ + (size_t)ce * 512 + 256;

        s8 af = zero_s8();
        if (q < 2) {
            const float* ap = &attr[(size_t)e * DIM_A + q * 8];
            float4 a0 = *(const float4*)ap;
            float4 a1 = *(const float4*)(ap + 4);
            af[0] = (short)f2bf(a0.x); af[1] = (short)f2bf(a0.y);
            af[2] = (short)f2bf(a0.z); af[3] = (short)f2bf(a0.w);
            af[4] = (short)f2bf(a1.x); af[5] = (short)f2bf(a1.y);
            af[6] = (short)f2bf(a1.z); af[7] = (short)f2bf(a1.w);
        }

#pragma unroll
        for (int mt = 0; mt < 16; mt++) {
            f4 cz = {0.f, 0.f, 0.f, 0.f};
            f4 acc = __builtin_amdgcn_mfma_f32_16x16x32_bf16(wcf[mt], af, cz, 0, 0, 0);
            ushort4 pu = *(const ushort4*)(prow + pq_off(mt, q));
            ushort4 qu = *(const ushort4*)(qrow + pq_off(mt, q));
            float t0 = bf2f(pu.x) + bf2f(qu.x) + acc[0];
            float t1 = bf2f(pu.y) + bf2f(qu.y) + acc[1];
            float t2 = bf2f(pu.z) + bf2f(qu.z) + acc[2];
            float t3 = bf2f(pu.w) + bf2f(qu.w) + acc[3];
            ushort4 o;
            o.x = f2bf(fmaxf(t0, 0.f)); o.y = f2bf(fmaxf(t1, 0.f));
            o.z = f2bf(fmaxf(t2, 0.f)); o.w = f2bf(fmaxf(t3, 0.f));
            *(ushort4*)&u[l][mt * 16 + q * 4] = o;
        }

        f4 acc2 = {0.f, 0.f, 0.f, 0.f};
#pragma unroll
        for (int ks = 0; ks < 8; ks++) {
            s8 uf = *(const s8*)&u[l][ks * 32 + q * 8];
            s8 wf = *(const s8*)&We2t[(size_t)l * DIM_H + ks * 32 + q * 8];
            acc2 = __builtin_amdgcn_mfma_f32_16x16x32_bf16(wf, uf, acc2, 0, 0, 0);
        }
        *(float4*)&outp[(size_t)e * DIM_A + q * 4] =
            make_float4(acc2[0] + be2v.x, acc2[1] + be2v.y,
                        acc2[2] + be2v.z, acc2[3] + be2v.w);
    }
}
#endif

extern "C" void kernel_launch(void* const* d_in, const int* in_sizes, int n_in,
                              void* d_out, int out_size, void* d_ws, size_t ws_size,
                              hipStream_t stream) {
    (void)in_sizes; (void)n_in; (void)out_size; (void)ws_size;
    const float* x    = (const float*)d_in[0];
    const int*   ei   = (const int*)d_in[1];
    const float* attr = (const float*)d_in[2];
    const float* W1   = (const float*)d_in[3];
    const float* b1   = (const float*)d_in[4];
    const float* W2   = (const float*)d_in[5];
    const float* b2   = (const float*)d_in[6];
    const float* Wo1  = (const float*)d_in[7];
    const float* bo1  = (const float*)d_in[8];
    const float* Wo2  = (const float*)d_in[9];
    const float* bo2  = (const float*)d_in[10];
    const float* We1  = (const float*)d_in[11];
    const float* be1  = (const float*)d_in[12];
    const float* We2  = (const float*)d_in[13];
    const float* be2  = (const float*)d_in[14];
    const int* rowi = ei;
    const int* coli = ei + N_EDGES;

    float* hout = (float*)d_out;                       // [N][128]
    float* eout = hout + (size_t)N_NODES * DIM_D;      // [E][16]

    char* ws = (char*)d_ws;
    size_t off = 0;
    auto nxt = [&](size_t b) -> void* {
        void* p = ws + off; off = (off + b + 255) & ~(size_t)255; return p;
    };
    float* dinv = (float*)nxt((size_t)N_NODES * 4);
    int* cnt    = (int*)nxt((size_t)N_NODES * 4);
    int* startp = (int*)nxt((size_t)(N_NODES + 1) * 4);
    int* cursor = (int*)nxt((size_t)N_NODES * 4);
    int2* pack  = (int2*)nxt((size_t)N_EDGES * 8);
    int2* eidx  = (int2*)nxt((size_t)N_EDGES * 8);
    u16* W1t   = (u16*)nxt(128 * 256 * 2);
    u16* W2t   = (u16*)nxt(128 * 256 * 2);
    u16* Wo1t  = (u16*)nxt(128 * 256 * 2);
    u16* Wo2t  = (u16*)nxt(128 * 256 * 2);
    u16* Wabt  = (u16*)nxt(512 * 128 * 2);   // [512][128]: Wa^T | Wb^T
    u16* Wct   = (u16*)nxt(256 * 16 * 2);
    u16* We2t  = (u16*)nxt(16 * 256 * 2);
    float* bpq = (float*)nxt(512 * 4);
    u16* xb    = (u16*)nxt((size_t)N_NODES * DIM_D * 2);     // x cast to bf16
    float* z   = (float*)nxt((size_t)N_NODES * DIM_D * 4);   // Âx / Ây accumulator (fp32)
    u16* h1    = (u16*)nxt((size_t)N_NODES * DIM_H * 2);     // intermediate [N][256]
    u16* yb    = (u16*)nxt((size_t)N_NODES * DIM_D * 2);
    // PQ [N][512] bf16 (51.2 MB) overlays z+h1 (both dead once hout is computed)
    u16* PQb = (u16*)z;

    const int gN = (N_NODES + 255) / 256;
    const int gE = (N_EDGES + 255) / 256;

    // weight transposes (bf16)
    k_twt<<<(128 * 256 + 255) / 256, 256, 0, stream>>>(W1, W1t, 128, 256);
    k_twt<<<(128 * 256 + 255) / 256, 256, 0, stream>>>(W2, W2t, 256, 128);
    k_twt<<<(128 * 256 + 255) / 256, 256, 0, stream>>>(Wo1, Wo1t, 128, 256);
    k_twt<<<(128 * 256 + 255) / 256, 256, 0, stream>>>(Wo2, Wo2t, 256, 128);
    k_twt<<<(128 * 256 + 255) / 256, 256, 0, stream>>>(We1, Wabt, 128, 256);
    k_twt<<<(128 * 256 + 255) / 256, 256, 0, stream>>>(We1 + 128 * 256, Wabt + 256 * 128, 128, 256);
    k_twt<<<(16 * 256 + 255) / 256, 256, 0, stream>>>(We1 + 256 * 256, Wct, 16, 256);
    k_twt<<<(16 * 256 + 255) / 256, 256, 0, stream>>>(We2, We2t, 256, 16);
    k_bpq<<<2, 256, 0, stream>>>(be1, bpq);

    // ---- CSR build (once; reused by both gather layers + edge predictor order) ----
    k_zero<<<gN, 256, 0, stream>>>(cnt);
    k_count<<<gE, 256, 0, stream>>>(coli, cnt);
    k_dinv<<<gN, 256, 0, stream>>>(cnt, dinv);
    k_scan<<<1, 1024, 0, stream>>>(cnt, startp);
    k_copy<<<gN, 256, 0, stream>>>(startp, cursor);
    k_fill<<<gE, 256, 0, stream>>>(rowi, coli, dinv, cursor, pack, eidx);

    // cast x -> bf16 (halves layer-1 gather traffic)
    k_cast<<<(N_NODES * DIM_D / 4 + 255) / 256, 256, 0, stream>>>(x, xb, N_NODES * DIM_D / 4);

    dim3 g4(391, 4), g2(391, 2), g8(391, 8);
    const int gG = (N_NODES + 3) / 4;   // 4 nodes (waves) per block
    // layer 1: z = Âx ; h1 = relu(z@W1 + b1)
    k_gather<<<gG, 256, 0, stream>>>(xb, pack, startp, dinv, z);
    k_gemm<false, false, true, true, false><<<g4, 256, 0, stream>>>(z, W1t, nullptr, b1, h1, N_NODES, 128, 256);
    // layer 2: y = h1@W2 ; z = Ây ; h2 = relu(z + b2) fused into next GEMM's A-stage
    k_gemm<true, false, false, true, false><<<g2, 256, 0, stream>>>(h1, W2t, nullptr, nullptr, yb, N_NODES, 256, 128);
    k_gather<<<gG, 256, 0, stream>>>(yb, pack, startp, dinv, z);
    // output MLP: h3 = relu(relu(z+b2)@Wo1 + bo1) ; h = h3@Wo2 + bo2 -> d_out (fp32)
    k_gemm<false, true, true, true, false><<<g4, 256, 0, stream>>>(z, Wo1t, b2, bo1, h1, N_NODES, 128, 256);
    k_gemm<true, false, false, false, false><<<g2, 256, 0, stream>>>(h1, Wo2t, nullptr, bo2, hout, N_NODES, 256, 128);
    // edge predictor precompute (single fused GEMM): PQ = [h@Wa + be1 | h@Wb]  (bf16, [N][512], permuted cols)
    k_gemm<false, false, false, true, true><<<g8, 256, 0, stream>>>(hout, Wabt, nullptr, bpq, PQb, N_NODES, 128, 512);
    // per-edge (CSR slot order): out = relu(P[src]+Q[dst]+attr@Wc)@We2 + be2
    k_edge<<<2048, 256, 0, stream>>>(PQb, attr, pack, eidx, Wct, We2t, be2, eout);
}